// Round 7
// baseline (624.430 us; speedup 1.0000x reference)
//
#include <hip/hip_runtime.h>
#include <hip/hip_bf16.h>
#include <cstddef>
#include <cstdint>

#define NN 16384
#define EE (9*NN)
#define CC 512

typedef __attribute__((ext_vector_type(4))) float f32x4;
typedef __attribute__((ext_vector_type(8))) short bf16x8;

static inline int idiv(int a, int b){ return (a+b-1)/b; }

__device__ __forceinline__ float bf2f(unsigned short u){
    union{unsigned u; float f;} v; v.u = ((unsigned)u) << 16; return v.f;
}
__device__ __forceinline__ unsigned short f2bf(float f){
    union{float f; unsigned u;} v; v.f = f;
    unsigned r = v.u + 0x7fffu + ((v.u >> 16) & 1u);
    return (unsigned short)(r >> 16);
}

__device__ __forceinline__ void gload16(const void* gsrc, void* ldst){
    __builtin_amdgcn_global_load_lds(
        (const __attribute__((address_space(1))) unsigned int*)gsrc,
        (__attribute__((address_space(3))) unsigned int*)ldst,
        16, 0, 0);
}

// ---------------- utility kernels ----------------

__global__ void zero_i(int* __restrict__ p, int n){
    int i = blockIdx.x*256 + threadIdx.x; if (i < n) p[i] = 0;
}

// fused column-sum + fp32->bf16 convert (UNcentered output), z-merged.
__global__ void colsum_cvt(const float* __restrict__ F0, float* __restrict__ cs0,
                           ushort4* __restrict__ o0,
                           const float* __restrict__ F1, float* __restrict__ cs1,
                           ushort4* __restrict__ o1){
    const float* F = blockIdx.z ? F1 : F0;
    float* cs = blockIdx.z ? cs1 : cs0;
    ushort4* o = blockIdx.z ? o1 : o0;
    const int RPB = NN/256;
    int r0 = blockIdx.x * RPB;
    int c4 = threadIdx.x;                     // 0..127
    float4 s = {0.f,0.f,0.f,0.f};
    for (int r = 0; r < RPB; ++r){
        float4 v = ((const float4*)(F + (size_t)(r0+r)*CC))[c4];
        s.x += v.x; s.y += v.y; s.z += v.z; s.w += v.w;
        ushort4 u;
        u.x = f2bf(v.x); u.y = f2bf(v.y); u.z = f2bf(v.z); u.w = f2bf(v.w);
        o[(size_t)(r0+r)*(CC/4) + c4] = u;
    }
    atomicAdd(&cs[c4*4+0], s.x);
    atomicAdd(&cs[c4*4+1], s.y);
    atomicAdd(&cs[c4*4+2], s.z);
    atomicAdd(&cs[c4*4+3], s.w);
}

// mw[colp] = (1/NN) * sum_c cs[c] * W[s][c][j]   (colp = s*Cout + j, zero-padded)
__global__ void mw_k(const float* __restrict__ W0, const float* __restrict__ cs0,
                     float* __restrict__ mw0,
                     const float* __restrict__ W1, const float* __restrict__ cs1,
                     float* __restrict__ mw1,
                     int S, int K, int Cout, int Npad){
    const float* W = blockIdx.z ? W1 : W0;
    const float* cs = blockIdx.z ? cs1 : cs0;
    float* mw = blockIdx.z ? mw1 : mw0;
    int colp = blockIdx.x*256 + threadIdx.x;
    if (colp >= Npad) return;
    int s = colp / Cout, j = colp - s*Cout;
    float acc = 0.f;
    if (s < S){
        for (int c = 0; c < K; ++c) acc += cs[c] * W[((size_t)s*K + c)*Cout + j];
    }
    mw[colp] = acc * (1.f/NN);
}

// generic weight transpose (small weights), z-selectable pair
__global__ void wtransz(const float* __restrict__ W0, unsigned short* __restrict__ Wt0,
                        const float* __restrict__ W1, unsigned short* __restrict__ Wt1,
                        int S, int K, int Cout, int Npad, int Kpad){
    const float* W = blockIdx.z ? W1 : W0;
    unsigned short* Wt = blockIdx.z ? Wt1 : Wt0;
    int idx = blockIdx.x*256 + threadIdx.x;
    if (idx >= Npad*Kpad) return;
    int colp = idx / Kpad, k = idx - colp*Kpad;
    int s = colp / Cout, j = colp - s*Cout;
    float v = 0.f;
    if (s < S && k < K) v = W[((size_t)s*K + k)*Cout + j];
    Wt[idx] = f2bf(v);
}

// fast LDS-tiled transpose, z-merged over 2 nets x 9 selections
__global__ void wtrans2z(const float* __restrict__ W0, const float* __restrict__ W1,
                         unsigned short* __restrict__ Wt0, unsigned short* __restrict__ Wt1,
                         int K, int Cout){
    __shared__ float tile[32][129];
    int s = blockIdx.z % 9;
    const float* W = (blockIdx.z < 9) ? W0 : W1;
    unsigned short* Wt = (blockIdx.z < 9) ? Wt0 : Wt1;
    int jb = blockIdx.x*128, kb = blockIdx.y*32;
    const float* Ws = W + (size_t)s*K*Cout;
    for (int r = 0; r < 32; ++r)
        tile[r][threadIdx.x] = Ws[(size_t)(kb+r)*Cout + jb + threadIdx.x];
    __syncthreads();
    int kk = threadIdx.x & 31, j0 = threadIdx.x >> 5;
    for (int jj = j0; jj < 128; jj += 4)
        Wt[(size_t)(s*Cout + jb + jj)*K + kb + kk] = f2bf(tile[kk][jj]);
}

// ---------------- CSR build (z-merged) ----------------
__global__ void csr_count3(const int* __restrict__ cDst, const int* __restrict__ sDst,
                           const int* __restrict__ cSel,
                           int* __restrict__ cCnt, int* __restrict__ sCnt, int* __restrict__ cCnt0){
    int e = blockIdx.x*256 + threadIdx.x;
    if (e >= EE) return;
    int z = blockIdx.z;
    if (z == 0)      atomicAdd(&cCnt[cDst[e]], 1);
    else if (z == 1) atomicAdd(&sCnt[sDst[e]], 1);
    else if (cSel[e] == 0) atomicAdd(&cCnt0[cDst[e]], 1);
}
__global__ void csr_scan3(const int* __restrict__ c0, const int* __restrict__ c1,
                          const int* __restrict__ c2,
                          int* __restrict__ r0, int* __restrict__ r1, int* __restrict__ r2){
    const int* cnt = blockIdx.z==0 ? c0 : (blockIdx.z==1 ? c1 : c2);
    int* rowptr    = blockIdx.z==0 ? r0 : (blockIdx.z==1 ? r1 : r2);
    __shared__ int part[1024];
    int t = threadIdx.x;
    int base = t*16, s = 0;
    int local[16];
    #pragma unroll
    for (int i = 0; i < 16; ++i){ local[i] = s; s += cnt[base+i]; }
    part[t] = s; __syncthreads();
    for (int off = 1; off < 1024; off <<= 1){
        int v = (t >= off) ? part[t-off] : 0;
        __syncthreads();
        part[t] += v;
        __syncthreads();
    }
    int pre = (t == 0) ? 0 : part[t-1];
    #pragma unroll
    for (int i = 0; i < 16; ++i) rowptr[base+i] = pre + local[i];
    if (t == 1023) rowptr[NN] = part[1023];
}
__global__ void csr_fill3(const int* __restrict__ cSrc, const int* __restrict__ cDst,
                          const int* __restrict__ cSel,
                          const int* __restrict__ sSrc, const int* __restrict__ sDst,
                          const int* __restrict__ sSel,
                          const int* __restrict__ cRow, const int* __restrict__ sRow,
                          const int* __restrict__ cRow0,
                          int* __restrict__ cCur, int* __restrict__ sCur, int* __restrict__ cCur0,
                          int* __restrict__ cEl, int* __restrict__ sEl, int* __restrict__ cEl0){
    int e = blockIdx.x*256 + threadIdx.x;
    if (e >= EE) return;
    int z = blockIdx.z;
    if (z == 0){
        int d = cDst[e];
        int p = atomicAdd(&cCur[d], 1);
        cEl[cRow[d] + p] = (cSrc[e] << 4) | cSel[e];
    } else if (z == 1){
        int d = sDst[e];
        int p = atomicAdd(&sCur[d], 1);
        sEl[sRow[d] + p] = (sSrc[e] << 4) | sSel[e];
    } else if (cSel[e] == 0){
        int d = cDst[e];
        int p = atomicAdd(&cCur0[d], 1);
        cEl0[cRow0[d] + p] = cSrc[e];
    }
}

// ---------------- 128^2 MFMA GEMM (2-phase BK=64; proven round 5), z-selectable ----------------
// swapped-operand accumulator -> packed stores; optional per-column csub (fp32)
template<typename OutT>
__global__ __launch_bounds__(256, 2)
void mfma_gemm(const unsigned short* __restrict__ A0, const unsigned short* __restrict__ Bt0,
               OutT* __restrict__ C0, const float* __restrict__ csub0,
               const unsigned short* __restrict__ A1, const unsigned short* __restrict__ Bt1,
               OutT* __restrict__ C1, const float* __restrict__ csub1, int K, int N){
    const unsigned short* A  = blockIdx.z ? A1 : A0;
    const unsigned short* Bt = blockIdx.z ? Bt1 : Bt0;
    OutT* C = blockIdx.z ? C1 : C0;
    const float* csub = blockIdx.z ? csub1 : csub0;
    __shared__ __align__(16) unsigned short As[128*64];
    __shared__ __align__(16) unsigned short Bs[128*64];
    const int tid  = threadIdx.x;
    const int wave = tid >> 6, lane = tid & 63;
    const int row0 = blockIdx.y << 7, col0 = blockIdx.x << 7;
    const int wm = wave >> 1, wn = wave & 1;
    const int fr = lane & 15, fq = lane >> 4;
    f32x4 acc[4][4] = {};
    for (int k0 = 0; k0 < K; k0 += 64){
        __syncthreads();
        #pragma unroll
        for (int i = 0; i < 4; ++i){
            int chb = (wave*4 + i) * 64;
            int ch  = chb + lane;
            int r   = ch >> 3, c8 = ch & 7;
            gload16((const char*)(A  + (size_t)(row0 + r)*K + k0) + c8*16, As + chb*8);
            gload16((const char*)(Bt + (size_t)(col0 + r)*K + k0) + c8*16, Bs + chb*8);
        }
        __syncthreads();
        #pragma unroll
        for (int ks = 0; ks < 2; ++ks){
            bf16x8 av[4], bv[4];
            #pragma unroll
            for (int m = 0; m < 4; ++m)
                av[m] = *(const bf16x8*)(As + ((wm<<6)+(m<<4)+fr)*64 + (ks<<5) + (fq<<3));
            #pragma unroll
            for (int n = 0; n < 4; ++n)
                bv[n] = *(const bf16x8*)(Bs + ((wn<<6)+(n<<4)+fr)*64 + (ks<<5) + (fq<<3));
            #pragma unroll
            for (int m = 0; m < 4; ++m)
                #pragma unroll
                for (int n = 0; n < 4; ++n)
                    acc[m][n] = __builtin_amdgcn_mfma_f32_16x16x32_bf16(bv[n], av[m], acc[m][n], 0, 0, 0);
        }
    }
    #pragma unroll
    for (int m = 0; m < 4; ++m){
        int row = row0 + (wm<<6) + (m<<4) + fr;
        OutT* crow = C + (size_t)row*N + col0 + (wn<<6) + (fq<<2);
        #pragma unroll
        for (int n = 0; n < 4; ++n){
            float v0 = acc[m][n][0], v1 = acc[m][n][1], v2 = acc[m][n][2], v3 = acc[m][n][3];
            if (csub){
                float4 sub = *(const float4*)(csub + col0 + (wn<<6) + (fq<<2) + (n<<4));
                v0 -= sub.x; v1 -= sub.y; v2 -= sub.z; v3 -= sub.w;
            }
            if constexpr (sizeof(OutT) == 2){
                unsigned lo = f2bf(v0) | ((unsigned)f2bf(v1) << 16);
                unsigned hi = f2bf(v2) | ((unsigned)f2bf(v3) << 16);
                uint2 pk; pk.x = lo; pk.y = hi;
                *(uint2*)((unsigned short*)crow + (n<<4)) = pk;
            } else {
                float4 pk; pk.x = v0; pk.y = v1; pk.z = v2; pk.w = v3;
                *(float4*)((float*)crow + (n<<4)) = pk;
            }
        }
    }
}

// ---------------- 256^2 8-phase GEMM (round-5 proven; used for L2) ----------------
template<int MQ, int NQ>
__device__ __forceinline__ void mfmaq(f32x4 (&acc)[8][4], bf16x8 (&a)[4][2], bf16x8 (&b)[2][2]){
    #pragma unroll
    for (int m = 0; m < 4; ++m)
        #pragma unroll
        for (int n = 0; n < 2; ++n)
            #pragma unroll
            for (int ks = 0; ks < 2; ++ks)
                acc[MQ*4+m][NQ*2+n] = __builtin_amdgcn_mfma_f32_16x16x32_bf16(
                    b[n][ks], a[m][ks], acc[MQ*4+m][NQ*2+n], 0, 0, 0);
}

#define MIDBAR() do{ __builtin_amdgcn_s_barrier(); \
                     asm volatile("s_waitcnt lgkmcnt(0)" ::: "memory"); \
                     __builtin_amdgcn_sched_barrier(0); \
                     __builtin_amdgcn_s_setprio(1); }while(0)
#define ENDBAR() do{ __builtin_amdgcn_s_setprio(0); \
                     __builtin_amdgcn_s_barrier(); }while(0)

template<int NK>
__global__ __launch_bounds__(512, 1)
void gemm8p(const unsigned short* __restrict__ Ain0, const unsigned short* __restrict__ Btin0,
            unsigned short* __restrict__ Cout0,
            const unsigned short* __restrict__ Ain1, const unsigned short* __restrict__ Btin1,
            unsigned short* __restrict__ Cout1, int N){
    constexpr int LDK = NK*64;
    const unsigned short* A  = blockIdx.z ? Ain1 : Ain0;
    const unsigned short* Bt = blockIdx.z ? Btin1 : Btin0;
    unsigned short* C = blockIdx.z ? Cout1 : Cout0;
    __shared__ __align__(16) unsigned short lds[2][4][8192];
    const int tid = threadIdx.x, w = tid >> 6, l = tid & 63;
    const int nbx = gridDim.x;
    const int nwg = gridDim.x * gridDim.y;
    int blin = blockIdx.y * nbx + blockIdx.x;
    int sw = (blin & 7) * (nwg >> 3) + (blin >> 3);
    const int bx = sw % nbx, by = sw / nbx;
    const int row0 = by << 8, col0 = bx << 8;
    const int wm = w >> 2, wn = w & 3;
    const int fr = l & 15, fq = l >> 4;

    f32x4 acc[8][4] = {};
    bf16x8 a[4][2], b01[2][2], b23[2][2];

    const unsigned short* gA = A + (size_t)row0 * LDK;
    const unsigned short* gB = Bt + (size_t)col0 * LDK;

    auto STG = [&](const unsigned short* gbase, int t, int half, unsigned short* ldsHalf){
        #pragma unroll
        for (int s = 0; s < 2; ++s){
            int o = s*8192 + w*1024 + l*16;
            int q = o ^ ((o >> 3) & 0x70);
            int row = q >> 7;
            gload16((const char*)(gbase + (size_t)(half*128 + row)*LDK + t*64) + (q & 127),
                    ldsHalf + s*4096 + w*512);
        }
    };
    auto LDA = [&](const unsigned short* half, int rb, int ks){
        int lg = (rb*16 + fr)*128 + ks*64 + fq*16;
        int ph = lg ^ ((fr & 7) << 4);
        return *(const bf16x8*)((const char*)half + ph);
    };

    STG(gA, 0, 0, &lds[0][0][0]); STG(gA, 0, 1, &lds[0][1][0]);
    STG(gB, 0, 0, &lds[0][2][0]); STG(gB, 0, 1, &lds[0][3][0]);
    STG(gB, 1, 0, &lds[1][2][0]); STG(gB, 1, 1, &lds[1][3][0]);
    asm volatile("s_waitcnt vmcnt(4)" ::: "memory");
    __builtin_amdgcn_s_barrier();

    const unsigned short* myA[2] = { &lds[0][wm][0], &lds[1][wm][0] };
    const unsigned short* myB[2] = { &lds[0][2+(wn>>1)][0], &lds[1][2+(wn>>1)][0] };
    const int brb = (wn & 1) * 4;

    for (int i = 0; i < NK/2; ++i){
        const int t0 = 2*i, t1 = 2*i + 1;
        #pragma unroll
        for (int m = 0; m < 4; ++m){ a[m][0] = LDA(myA[0], m, 0); a[m][1] = LDA(myA[0], m, 1); }
        #pragma unroll
        for (int n = 0; n < 2; ++n){ b01[n][0] = LDA(myB[0], brb+n, 0); b01[n][1] = LDA(myB[0], brb+n, 1); }
        STG(gA, t1, 0, &lds[1][0][0]);
        MIDBAR(); mfmaq<0,0>(acc, a, b01); ENDBAR();
        #pragma unroll
        for (int n = 0; n < 2; ++n){ b23[n][0] = LDA(myB[0], brb+2+n, 0); b23[n][1] = LDA(myB[0], brb+2+n, 1); }
        STG(gA, t1, 1, &lds[1][1][0]);
        MIDBAR(); mfmaq<0,1>(acc, a, b23); ENDBAR();
        #pragma unroll
        for (int m = 0; m < 4; ++m){ a[m][0] = LDA(myA[0], 4+m, 0); a[m][1] = LDA(myA[0], 4+m, 1); }
        STG(gB, t0+2, 0, &lds[0][2][0]);
        MIDBAR(); mfmaq<1,0>(acc, a, b01); ENDBAR();
        STG(gB, t0+2, 1, &lds[0][3][0]);
        asm volatile("s_waitcnt vmcnt(4)" ::: "memory");
        MIDBAR(); mfmaq<1,1>(acc, a, b23); ENDBAR();
        #pragma unroll
        for (int m = 0; m < 4; ++m){ a[m][0] = LDA(myA[1], m, 0); a[m][1] = LDA(myA[1], m, 1); }
        #pragma unroll
        for (int n = 0; n < 2; ++n){ b01[n][0] = LDA(myB[1], brb+n, 0); b01[n][1] = LDA(myB[1], brb+n, 1); }
        STG(gA, t0+2, 0, &lds[0][0][0]);
        MIDBAR(); mfmaq<0,0>(acc, a, b01); ENDBAR();
        #pragma unroll
        for (int n = 0; n < 2; ++n){ b23[n][0] = LDA(myB[1], brb+2+n, 0); b23[n][1] = LDA(myB[1], brb+2+n, 1); }
        STG(gA, t0+2, 1, &lds[0][1][0]);
        MIDBAR(); mfmaq<0,1>(acc, a, b23); ENDBAR();
        #pragma unroll
        for (int m = 0; m < 4; ++m){ a[m][0] = LDA(myA[1], 4+m, 0); a[m][1] = LDA(myA[1], 4+m, 1); }
        STG(gB, t1+2, 0, &lds[1][2][0]);
        MIDBAR(); mfmaq<1,0>(acc, a, b01); ENDBAR();
        STG(gB, t1+2, 1, &lds[1][3][0]);
        asm volatile("s_waitcnt vmcnt(4)" ::: "memory");
        MIDBAR(); mfmaq<1,1>(acc, a, b23); ENDBAR();
    }
    asm volatile("s_waitcnt vmcnt(0)" ::: "memory");

    #pragma unroll
    for (int m = 0; m < 8; ++m){
        int row = row0 + wm*128 + m*16 + fr;
        unsigned short* crow = C + (size_t)row*N + col0 + wn*64 + fq*4;
        #pragma unroll
        for (int n = 0; n < 4; ++n){
            unsigned lo = f2bf(acc[m][n][0]) | ((unsigned)f2bf(acc[m][n][1]) << 16);
            unsigned hi = f2bf(acc[m][n][2]) | ((unsigned)f2bf(acc[m][n][3]) << 16);
            uint2 pk; pk.x = lo; pk.y = hi;
            *(uint2*)(crow + (n<<4)) = pk;
        }
    }
}

// ---------------- 128^2 double-buffered GEMM BK=32 (measured-good for L1 only) ----------------
template<int NT, typename OutT>
__global__ __launch_bounds__(256, 3)
void gemm_db(const unsigned short* __restrict__ A0, const unsigned short* __restrict__ Bt0,
             OutT* __restrict__ C0, const float* __restrict__ csub0,
             const unsigned short* __restrict__ A1, const unsigned short* __restrict__ Bt1,
             OutT* __restrict__ C1, const float* __restrict__ csub1, int N){
    constexpr int LDK = NT*32;
    const unsigned short* A  = blockIdx.z ? A1 : A0;
    const unsigned short* Bt = blockIdx.z ? Bt1 : Bt0;
    OutT* C = blockIdx.z ? C1 : C0;
    const float* csub = blockIdx.z ? csub1 : csub0;
    __shared__ __align__(16) unsigned short lds[2][2][4096];
    const int tid = threadIdx.x, w = tid >> 6, l = tid & 63;
    const int wm = w >> 1, wn = w & 1;
    const int fr = l & 15, fq = l >> 4;
    const int nbx = gridDim.x;
    const int nwg = gridDim.x * gridDim.y;
    int blin = blockIdx.y * nbx + blockIdx.x;
    int sw = (blin & 7) * (nwg >> 3) + (blin >> 3);
    const int bx = sw % nbx, by = sw / nbx;
    const int row0 = by << 7, col0 = bx << 7;

    const unsigned short* gA = A + (size_t)row0 * LDK;
    const unsigned short* gB = Bt + (size_t)col0 * LDK;

    auto STG = [&](int buf, int t){
        #pragma unroll
        for (int mtx = 0; mtx < 2; ++mtx){
            const unsigned short* gb = mtx ? gB : gA;
            #pragma unroll
            for (int ld = 0; ld < 2; ++ld){
                int o = (ld*256 + tid) * 16;
                int row = o >> 6;
                int kb = (o & 63) ^ ((row & 3) << 4);
                gload16((const char*)(gb + (size_t)row*LDK + t*32) + kb,
                        (char*)&lds[buf][mtx][0] + o);
            }
        }
    };

    f32x4 acc[4][4] = {};
    STG(0, 0);
    __syncthreads();
    for (int t = 0; t < NT; ++t){
        int cur = t & 1;
        if (t + 1 < NT) STG(cur ^ 1, t + 1);
        bf16x8 av[4], bv[4];
        #pragma unroll
        for (int m = 0; m < 4; ++m){
            int r = wm*64 + m*16 + fr;
            int p = (r*64 + fq*16) ^ ((r & 3) << 4);
            av[m] = *(const bf16x8*)((const char*)&lds[cur][0][0] + p);
        }
        #pragma unroll
        for (int n = 0; n < 4; ++n){
            int r = wn*64 + n*16 + fr;
            int p = (r*64 + fq*16) ^ ((r & 3) << 4);
            bv[n] = *(const bf16x8*)((const char*)&lds[cur][1][0] + p);
        }
        #pragma unroll
        for (int m = 0; m < 4; ++m)
            #pragma unroll
            for (int n = 0; n < 4; ++n)
                acc[m][n] = __builtin_amdgcn_mfma_f32_16x16x32_bf16(bv[n], av[m], acc[m][n], 0, 0, 0);
        __syncthreads();
    }

    #pragma unroll
    for (int m = 0; m < 4; ++m){
        int row = row0 + wm*64 + m*16 + fr;
        OutT* crow = C + (size_t)row*N + col0 + (wn<<6) + (fq<<2);
        #pragma unroll
        for (int n = 0; n < 4; ++n){
            float v0 = acc[m][n][0], v1 = acc[m][n][1], v2 = acc[m][n][2], v3 = acc[m][n][3];
            if (csub){
                float4 sub = *(const float4*)(csub + col0 + (wn<<6) + (fq<<2) + (n<<4));
                v0 -= sub.x; v1 -= sub.y; v2 -= sub.z; v3 -= sub.w;
            }
            if constexpr (sizeof(OutT) == 2){
                unsigned lo = f2bf(v0) | ((unsigned)f2bf(v1) << 16);
                unsigned hi = f2bf(v2) | ((unsigned)f2bf(v3) << 16);
                uint2 pk; pk.x = lo; pk.y = hi;
                *(uint2*)((unsigned short*)crow + (n<<4)) = pk;
            } else {
                float4 pk; pk.x = v0; pk.y = v1; pk.z = v2; pk.w = v3;
                *(float4*)((float*)crow + (n<<4)) = pk;
            }
        }
    }
}

// ---------------- vectorized CSR gathers (z-merged over nets) ----------------
template<typename TO, bool RELU>
__global__ void gather8z(const int* __restrict__ rp0, const int* __restrict__ el0,
                         const unsigned short* __restrict__ t0, const float* __restrict__ b0,
                         TO* __restrict__ o0,
                         const int* __restrict__ rp1, const int* __restrict__ el1,
                         const unsigned short* __restrict__ t1, const float* __restrict__ b1,
                         TO* __restrict__ o1,
                         int tStride, int coutShift){
    const int* rowptr = blockIdx.z ? rp1 : rp0;
    const int* elist  = blockIdx.z ? el1 : el0;
    const unsigned short* t = blockIdx.z ? t1 : t0;
    const float* bias = blockIdx.z ? b1 : b0;
    TO* out = blockIdx.z ? o1 : o0;
    int idx = blockIdx.x*256 + threadIdx.x;
    int chSh = coutShift - 3;
    int d = idx >> chSh;
    int c0 = (idx & ((1 << chSh) - 1)) << 3;
    float acc[8];
    {
        const float4* bb = (const float4*)(bias + c0);
        float4 a = bb[0], b = bb[1];
        acc[0]=a.x; acc[1]=a.y; acc[2]=a.z; acc[3]=a.w;
        acc[4]=b.x; acc[5]=b.y; acc[6]=b.z; acc[7]=b.w;
    }
    int j1 = rowptr[d+1];
    #pragma unroll 2
    for (int j = rowptr[d]; j < j1; ++j){
        int p = elist[j];
        int s = p & 15, sr = p >> 4;
        bf16x8 v = *(const bf16x8*)(t + (size_t)sr*tStride + (s << coutShift) + c0);
        #pragma unroll
        for (int k = 0; k < 8; ++k) acc[k] += bf2f((unsigned short)v[k]);
    }
    if (RELU){
        #pragma unroll
        for (int k = 0; k < 8; ++k) acc[k] = fmaxf(acc[k], 0.f);
    }
    if constexpr (sizeof(TO) == 2){
        union { bf16x8 v; unsigned short u[8]; } r;
        #pragma unroll
        for (int k = 0; k < 8; ++k) r.u[k] = f2bf(acc[k]);
        *(bf16x8*)((unsigned short*)out + ((size_t)d << coutShift) + c0) = r.v;
    } else {
        float4 a = {acc[0],acc[1],acc[2],acc[3]};
        float4 b = {acc[4],acc[5],acc[6],acc[7]};
        float4* op = (float4*)((float*)out + ((size_t)d << coutShift) + c0);
        op[0] = a; op[1] = b;
    }
}

template<bool ADDV>
__global__ void gather4f(const int* __restrict__ rowptr, const int* __restrict__ elist,
                         const float* __restrict__ t,
                         const float* __restrict__ bias, const float* __restrict__ addvec,
                         float* __restrict__ out, int tStride, int coutShift){
    int idx = blockIdx.x*256 + threadIdx.x;
    int chSh = coutShift - 2;
    int d = idx >> chSh;
    int c0 = (idx & ((1 << chSh) - 1)) << 2;
    float4 bb = *(const float4*)(bias + c0);
    float acc0 = bb.x, acc1 = bb.y, acc2 = bb.z, acc3 = bb.w;
    if (ADDV){
        float4 av = *(const float4*)(addvec + c0);
        acc0 += av.x*(1.f/NN); acc1 += av.y*(1.f/NN);
        acc2 += av.z*(1.f/NN); acc3 += av.w*(1.f/NN);
    }
    int j1 = rowptr[d+1];
    #pragma unroll 2
    for (int j = rowptr[d]; j < j1; ++j){
        int sr = elist[j];
        float4 v = *(const float4*)(t + (size_t)sr*tStride + c0);
        acc0 += v.x; acc1 += v.y; acc2 += v.z; acc3 += v.w;
    }
    float4 r = {acc0, acc1, acc2, acc3};
    *(float4*)(out + ((size_t)d << coutShift) + c0) = r;
}

// ---------------- gram / fc (z-merged), tf (fused T-compute) ----------------
__global__ void gram2(const float* __restrict__ h0, float* __restrict__ g0,
                      const float* __restrict__ h1, float* __restrict__ g1){
    const float* h = blockIdx.z ? h1 : h0;
    float* g = blockIdx.z ? g1 : g0;
    const int RPB = NN/64;
    int r0 = blockIdx.x*RPB;
    int i = threadIdx.x >> 5, j = threadIdx.x & 31;
    float s = 0.f;
    for (int r = 0; r < RPB; ++r){
        const float* row = h + (size_t)(r0+r)*32;
        s += row[i]*row[j];
    }
    atomicAdd(&g[threadIdx.x], s);
}

__global__ void fc2(const float* __restrict__ g0, const float* __restrict__ fcW0,
                    const float* __restrict__ fcb0, float* __restrict__ o0,
                    const float* __restrict__ g1, const float* __restrict__ fcW1,
                    const float* __restrict__ fcb1, float* __restrict__ o1){
    const float* g   = blockIdx.z ? g1 : g0;
    const float* fcW = blockIdx.z ? fcW1 : fcW0;
    const float* fcb = blockIdx.z ? fcb1 : fcb0;
    float* outMat    = blockIdx.z ? o1 : o0;
    int i = blockIdx.x;
    float s = 0.f;
    for (int j = threadIdx.x; j < 1024; j += 256)
        s += g[j] * (1.f/NN) * fcW[(size_t)i*1024 + j];
    __shared__ float red[256];
    red[threadIdx.x] = s; __syncthreads();
    for (int off = 128; off > 0; off >>= 1){
        if (threadIdx.x < off) red[threadIdx.x] += red[threadIdx.x+off];
        __syncthreads();
    }
    if (threadIdx.x == 0) outMat[i] = red[0] + fcb[i];
}

__global__ void tf_cvt2(const float* __restrict__ cc, const float* __restrict__ sM,
                        const float* __restrict__ cM, float* __restrict__ Tout,
                        unsigned short* __restrict__ tfbB){
    __shared__ float Ts[1024];
    for (int e = threadIdx.x; e < 1024; e += 256){
        int i = e >> 5, j = e & 31;
        float s = 0.f;
        #pragma unroll
        for (int k = 0; k < 32; ++k) s += sM[i*32+k]*cM[k*32+j];
        Ts[e] = s;
        if (blockIdx.x == 0) Tout[e] = s;
    }
    __syncthreads();
    int idx = blockIdx.x*256 + threadIdx.x;
    int n = idx >> 5, i = idx & 31;
    float s = 0.f;
    const float* crow = cc + (size_t)n*32;
    #pragma unroll
    for (int j = 0; j < 32; ++j) s += crow[j] * Ts[i*32+j];
    tfbB[(size_t)n*64 + i] = f2bf(s);
    tfbB[(size_t)n*64 + 32 + i] = 0;
}

extern "C" void kernel_launch(void* const* d_in, const int* in_sizes, int n_in,
                              void* d_out, int out_size, void* d_ws, size_t ws_size,
                              hipStream_t stream){
    const float* cF   = (const float*)d_in[0];
    const float* sF   = (const float*)d_in[1];
    const int*   cEI  = (const int*)d_in[2];
    const int*   cSel = (const int*)d_in[3];
    const int*   sEI  = (const int*)d_in[4];
    const int*   sSel = (const int*)d_in[5];
    const float* compW= (const float*)d_in[6];
    const float* compB= (const float*)d_in[7];
    const float* unzW = (const float*)d_in[8];
    const float* unzB = (const float*)d_in[9];
    const float* cW1=(const float*)d_in[10]; const float* cB1=(const float*)d_in[11];
    const float* cW2=(const float*)d_in[12]; const float* cB2=(const float*)d_in[13];
    const float* cW3=(const float*)d_in[14]; const float* cB3=(const float*)d_in[15];
    const float* cFW=(const float*)d_in[16]; const float* cFB=(const float*)d_in[17];
    const float* sW1=(const float*)d_in[18]; const float* sB1=(const float*)d_in[19];
    const float* sW2=(const float*)d_in[20]; const float* sB2=(const float*)d_in[21];
    const float* sW3=(const float*)d_in[22]; const float* sB3=(const float*)d_in[23];
    const float* sFW=(const float*)d_in[24]; const float* sFB=(const float*)d_in[25];

    float* out  = (float*)d_out;
    float* Tmat = out + (size_t)NN*CC;

    // ---- workspace carve (~193 MB) ----
    char* w = (char*)d_ws;
    auto alloc = [&](size_t b)->char*{ char* p = w; w += (b + 255) & ~(size_t)255; return p; };
    float* cCol = (float*)alloc(512*4);
    float* sCol = (float*)alloc(512*4);
    float* cg   = (float*)alloc(1024*4);
    float* sg   = (float*)alloc(1024*4);
    float* cMat = (float*)alloc(1024*4);
    float* sMat = (float*)alloc(1024*4);
    int* cCnt = (int*)alloc(NN*4);
    int* cCur = (int*)alloc(NN*4);
    int* sCnt = (int*)alloc(NN*4);
    int* sCur = (int*)alloc(NN*4);
    int* cCnt0= (int*)alloc(NN*4);
    int* cCur0= (int*)alloc(NN*4);
    int* cRow = (int*)alloc((NN+1)*4);
    int* sRow = (int*)alloc((NN+1)*4);
    int* cRow0= (int*)alloc((NN+1)*4);
    int* cEl  = (int*)alloc(EE*4);
    int* sEl  = (int*)alloc(EE*4);
    int* cEl0 = (int*)alloc(EE*4);
    float* ccbuf = (float*)alloc((size_t)NN*32*4);
    unsigned short* tfbB = (unsigned short*)alloc((size_t)NN*64*2);
    float* mwC1 = (float*)alloc(2304*4);
    float* mwS1 = (float*)alloc(2304*4);
    float* mwCo = (float*)alloc(128*4);
    unsigned short* wtC1 = (unsigned short*)alloc((size_t)2304*512*2);
    unsigned short* wtC2 = (unsigned short*)alloc((size_t)1280*256*2);
    unsigned short* wtC3 = (unsigned short*)alloc((size_t)384*128*2);
    unsigned short* wtS1 = (unsigned short*)alloc((size_t)2304*512*2);
    unsigned short* wtS2 = (unsigned short*)alloc((size_t)1280*256*2);
    unsigned short* wtS3 = (unsigned short*)alloc((size_t)384*128*2);
    unsigned short* wtCo = (unsigned short*)alloc((size_t)128*512*2);
    unsigned short* wtU  = (unsigned short*)alloc((size_t)512*64*2);
    unsigned short* xBc = (unsigned short*)alloc((size_t)NN*512*2);
    unsigned short* xBs = (unsigned short*)alloc((size_t)NN*512*2);
    float* h3c = (float*)alloc((size_t)NN*32*4);
    float* h3s = (float*)alloc((size_t)NN*32*4);
    unsigned short* tC = (unsigned short*)alloc((size_t)NN*2304*2);
    unsigned short* tS = (unsigned short*)alloc((size_t)NN*2304*2);
    float* tFc = (float*)tC;
    unsigned short* h1c = xBc;
    unsigned short* h1s = xBs;
    unsigned short* h2c = xBc + (size_t)NN*256;
    unsigned short* h2s = xBs + (size_t)NN*256;

    const int* cSrc = cEI; const int* cDst = cEI + EE;
    const int* sSrc = sEI; const int* sDst = sEI + EE;

    // ---- zero the contiguous accumulator block ----
    int zeroInts = (int)(((char*)cCur0 - (char*)d_ws)/4) + NN;
    zero_i<<<idiv(zeroInts,256),256,0,stream>>>((int*)d_ws, zeroInts);

    // ---- fused colsum + bf16 convert (centering folded into GEMM csub) ----
    colsum_cvt<<<dim3(256,1,2),128,0,stream>>>(cF, cCol, (ushort4*)xBc,
                                               sF, sCol, (ushort4*)xBs);

    // ---- weight transposes ----
    wtrans2z<<<dim3(2,16,18),128,0,stream>>>(cW1, sW1, wtC1, wtS1, 512, 256);
    wtrans2z<<<dim3(1,8,18),128,0,stream>>>(cW2, sW2, wtC2, wtS2, 256, 128);
    wtransz<<<dim3(idiv(384*128,256),1,2),256,0,stream>>>(cW3, wtC3, sW3, wtS3, 9,128,32, 384,128);
    wtransz<<<dim3(idiv(128*512,256),1,1),256,0,stream>>>(compW, wtCo, compW, wtCo, 1,512,32, 128,512);
    wtransz<<<dim3(idiv(512*64,256),1,1),256,0,stream>>>(unzW, wtU, unzW, wtU, 1,32,512, 512,64);

    // ---- mean@W correction vectors ----
    mw_k<<<dim3(9,1,2),256,0,stream>>>(cW1, cCol, mwC1, sW1, sCol, mwS1, 9,512,256, 2304);
    mw_k<<<dim3(1,1,1),256,0,stream>>>(compW, cCol, mwCo, compW, cCol, mwCo, 1,512,32, 128);

    // ---- CSR build (merged) ----
    csr_count3<<<dim3(idiv(EE,256),1,3),256,0,stream>>>(cDst, sDst, cSel, cCnt, sCnt, cCnt0);
    csr_scan3<<<dim3(1,1,3),1024,0,stream>>>(cCnt, sCnt, cCnt0, cRow, sRow, cRow0);
    csr_fill3<<<dim3(idiv(EE,256),1,3),256,0,stream>>>(cSrc,cDst,cSel, sSrc,sDst,sSel,
                                                       cRow,sRow,cRow0, cCur,sCur,cCur0,
                                                       cEl,sEl,cEl0);

    // ---- compress: tF = x@compW - mwCo ; cc = bias + gather(sel==0) ----
    mfma_gemm<float><<<dim3(1,128,1),256,0,stream>>>(xBc, wtCo, tFc, mwCo,
                                                     xBc, wtCo, tFc, mwCo, 512, 128);
    gather4f<false><<<NN*8/256,256,0,stream>>>(cRow0,cEl0,tFc,compB,nullptr,ccbuf,128,5);

    // ---- L1 (both nets): t = x@W1 - mw1 (gemm_db, measured 130us) ----
    gemm_db<16,unsigned short><<<dim3(18,128,2),256,0,stream>>>(xBc, wtC1, tC, mwC1,
                                                                xBs, wtS1, tS, mwS1, 2304);
    gather8z<unsigned short,true><<<dim3(2048,1,2),256,0,stream>>>(
        cRow,cEl,tC,cB1,h1c, sRow,sEl,tS,sB1,h1s, 2304, 8);
    // ---- L2 (both nets): round-5 gemm8p ----
    gemm8p<4><<<dim3(5,64,2),512,0,stream>>>(h1c, wtC2, tC, h1s, wtS2, tS, 1280);
    gather8z<unsigned short,true><<<dim3(1024,1,2),256,0,stream>>>(
        cRow,cEl,tC,cB2,h2c, sRow,sEl,tS,sB2,h2s, 1280, 7);
    // ---- L3 (both nets): round-5 mfma_gemm ----
    mfma_gemm<unsigned short><<<dim3(3,128,2),256,0,stream>>>(h2c, wtC3, tC, nullptr,
                                                              h2s, wtS3, tS, nullptr, 128, 384);
    gather8z<float,false><<<dim3(256,1,2),256,0,stream>>>(
        cRow,cEl,tC,cB3,h3c, sRow,sEl,tS,sB3,h3s, 384, 5);
    // ---- gram + fc (both nets) ----
    gram2<<<dim3(64,1,2),1024,0,stream>>>(h3c, cg, h3s, sg);
    fc2<<<dim3(1024,1,2),256,0,stream>>>(cg,cFW,cFB,cMat, sg,sFW,sFB,sMat);

    // ---- transmatrix (fused) + transfeature ----
    tf_cvt2<<<NN*32/256,256,0,stream>>>(ccbuf, sMat, cMat, Tmat, tfbB);

    // ---- unzip: out = unzip_b + sMean + gather(sel==0) of tf @ unzip_W ----
    mfma_gemm<float><<<dim3(4,128,1),256,0,stream>>>(tfbB, wtU, tFc, nullptr,
                                                     tfbB, wtU, tFc, nullptr, 64, 512);
    gather4f<true><<<NN*128/256,256,0,stream>>>(cRow0,cEl0,tFc,unzB,sCol,out,512,9);
}

// Round 8
// 420.628 us; speedup vs baseline: 1.4845x; 1.4845x over previous
//
#include <hip/hip_runtime.h>
#include <hip/hip_bf16.h>
#include <cstddef>
#include <cstdint>

#define NN 16384
#define EE (9*NN)
#define CC 512

typedef __attribute__((ext_vector_type(4))) float f32x4;
typedef __attribute__((ext_vector_type(8))) short bf16x8;

static inline int idiv(int a, int b){ return (a+b-1)/b; }

__device__ __forceinline__ float bf2f(unsigned short u){
    union{unsigned u; float f;} v; v.u = ((unsigned)u) << 16; return v.f;
}
__device__ __forceinline__ unsigned short f2bf(float f){
    union{float f; unsigned u;} v; v.f = f;
    unsigned r = v.u + 0x7fffu + ((v.u >> 16) & 1u);
    return (unsigned short)(r >> 16);
}

__device__ __forceinline__ void gload16(const void* gsrc, void* ldst){
    __builtin_amdgcn_global_load_lds(
        (const __attribute__((address_space(1))) unsigned int*)gsrc,
        (__attribute__((address_space(3))) unsigned int*)ldst,
        16, 0, 0);
}

// ---------------- utility kernels ----------------

__global__ void zero_i(int* __restrict__ p, int n){
    int i = blockIdx.x*256 + threadIdx.x; if (i < n) p[i] = 0;
}

// z-merged column sums of F[NN][CC] via float4; cs pre-zeroed.
__global__ void colsum2(const float* __restrict__ F0, float* __restrict__ cs0,
                        const float* __restrict__ F1, float* __restrict__ cs1){
    const float* F = blockIdx.z ? F1 : F0;
    float* cs = blockIdx.z ? cs1 : cs0;
    const int RPB = NN/256;
    int r0 = blockIdx.x * RPB;
    int c4 = threadIdx.x;
    float4 s = {0.f,0.f,0.f,0.f};
    for (int r = 0; r < RPB; ++r){
        float4 v = ((const float4*)(F + (size_t)(r0+r)*CC))[c4];
        s.x += v.x; s.y += v.y; s.z += v.z; s.w += v.w;
    }
    atomicAdd(&cs[c4*4+0], s.x);
    atomicAdd(&cs[c4*4+1], s.y);
    atomicAdd(&cs[c4*4+2], s.z);
    atomicAdd(&cs[c4*4+3], s.w);
}

__global__ void center2(const float* __restrict__ F0, const float* __restrict__ cs0,
                        ushort4* __restrict__ o0,
                        const float* __restrict__ F1, const float* __restrict__ cs1,
                        ushort4* __restrict__ o1){
    const float* F = blockIdx.z ? F1 : F0;
    const float* cs = blockIdx.z ? cs1 : cs0;
    ushort4* o = blockIdx.z ? o1 : o0;
    int i = blockIdx.x*256 + threadIdx.x;
    float4 v = ((const float4*)F)[i];
    int c = (i << 2) & (CC-1);
    float4 m = *(const float4*)(cs + c);
    ushort4 r;
    r.x = f2bf(v.x - m.x*(1.f/NN));
    r.y = f2bf(v.y - m.y*(1.f/NN));
    r.z = f2bf(v.z - m.z*(1.f/NN));
    r.w = f2bf(v.w - m.w*(1.f/NN));
    o[i] = r;
}

// generic weight transpose (small weights), z-selectable pair
__global__ void wtransz(const float* __restrict__ W0, unsigned short* __restrict__ Wt0,
                        const float* __restrict__ W1, unsigned short* __restrict__ Wt1,
                        int S, int K, int Cout, int Npad, int Kpad){
    const float* W = blockIdx.z ? W1 : W0;
    unsigned short* Wt = blockIdx.z ? Wt1 : Wt0;
    int idx = blockIdx.x*256 + threadIdx.x;
    if (idx >= Npad*Kpad) return;
    int colp = idx / Kpad, k = idx - colp*Kpad;
    int s = colp / Cout, j = colp - s*Cout;
    float v = 0.f;
    if (s < S && k < K) v = W[((size_t)s*K + k)*Cout + j];
    Wt[idx] = f2bf(v);
}

// fast LDS-tiled transpose, z-merged over 2 nets x 9 selections
__global__ void wtrans2z(const float* __restrict__ W0, const float* __restrict__ W1,
                         unsigned short* __restrict__ Wt0, unsigned short* __restrict__ Wt1,
                         int K, int Cout){
    __shared__ float tile[32][129];
    int s = blockIdx.z % 9;
    const float* W = (blockIdx.z < 9) ? W0 : W1;
    unsigned short* Wt = (blockIdx.z < 9) ? Wt0 : Wt1;
    int jb = blockIdx.x*128, kb = blockIdx.y*32;
    const float* Ws = W + (size_t)s*K*Cout;
    for (int r = 0; r < 32; ++r)
        tile[r][threadIdx.x] = Ws[(size_t)(kb+r)*Cout + jb + threadIdx.x];
    __syncthreads();
    int kk = threadIdx.x & 31, j0 = threadIdx.x >> 5;
    for (int jj = j0; jj < 128; jj += 4)
        Wt[(size_t)(s*Cout + jb + jj)*K + kb + kk] = f2bf(tile[kk][jj]);
}

// ---------------- CSR build (z-merged) ----------------
__global__ void csr_count3(const int* __restrict__ cDst, const int* __restrict__ sDst,
                           const int* __restrict__ cSel,
                           int* __restrict__ cCnt, int* __restrict__ sCnt, int* __restrict__ cCnt0){
    int e = blockIdx.x*256 + threadIdx.x;
    if (e >= EE) return;
    int z = blockIdx.z;
    if (z == 0)      atomicAdd(&cCnt[cDst[e]], 1);
    else if (z == 1) atomicAdd(&sCnt[sDst[e]], 1);
    else if (cSel[e] == 0) atomicAdd(&cCnt0[cDst[e]], 1);
}
__global__ void csr_scan3(const int* __restrict__ c0, const int* __restrict__ c1,
                          const int* __restrict__ c2,
                          int* __restrict__ r0, int* __restrict__ r1, int* __restrict__ r2){
    const int* cnt = blockIdx.z==0 ? c0 : (blockIdx.z==1 ? c1 : c2);
    int* rowptr    = blockIdx.z==0 ? r0 : (blockIdx.z==1 ? r1 : r2);
    __shared__ int part[1024];
    int t = threadIdx.x;
    int base = t*16, s = 0;
    int local[16];
    #pragma unroll
    for (int i = 0; i < 16; ++i){ local[i] = s; s += cnt[base+i]; }
    part[t] = s; __syncthreads();
    for (int off = 1; off < 1024; off <<= 1){
        int v = (t >= off) ? part[t-off] : 0;
        __syncthreads();
        part[t] += v;
        __syncthreads();
    }
    int pre = (t == 0) ? 0 : part[t-1];
    #pragma unroll
    for (int i = 0; i < 16; ++i) rowptr[base+i] = pre + local[i];
    if (t == 1023) rowptr[NN] = part[1023];
}
__global__ void csr_fill3(const int* __restrict__ cSrc, const int* __restrict__ cDst,
                          const int* __restrict__ cSel,
                          const int* __restrict__ sSrc, const int* __restrict__ sDst,
                          const int* __restrict__ sSel,
                          const int* __restrict__ cRow, const int* __restrict__ sRow,
                          const int* __restrict__ cRow0,
                          int* __restrict__ cCur, int* __restrict__ sCur, int* __restrict__ cCur0,
                          int* __restrict__ cEl, int* __restrict__ sEl, int* __restrict__ cEl0){
    int e = blockIdx.x*256 + threadIdx.x;
    if (e >= EE) return;
    int z = blockIdx.z;
    if (z == 0){
        int d = cDst[e];
        int p = atomicAdd(&cCur[d], 1);
        cEl[cRow[d] + p] = (cSrc[e] << 4) | cSel[e];
    } else if (z == 1){
        int d = sDst[e];
        int p = atomicAdd(&sCur[d], 1);
        sEl[sRow[d] + p] = (sSrc[e] << 4) | sSel[e];
    } else if (cSel[e] == 0){
        int d = cDst[e];
        int p = atomicAdd(&cCur0[d], 1);
        cEl0[cRow0[d] + p] = cSrc[e];
    }
}

// ---------------- 128^2 MFMA GEMM (2-phase BK=64; proven round 5), z-selectable ----------------
template<typename OutT>
__global__ __launch_bounds__(256, 2)
void mfma_gemm(const unsigned short* __restrict__ A0, const unsigned short* __restrict__ Bt0,
               OutT* __restrict__ C0,
               const unsigned short* __restrict__ A1, const unsigned short* __restrict__ Bt1,
               OutT* __restrict__ C1, int K, int N){
    const unsigned short* A  = blockIdx.z ? A1 : A0;
    const unsigned short* Bt = blockIdx.z ? Bt1 : Bt0;
    OutT* C = blockIdx.z ? C1 : C0;
    __shared__ __align__(16) unsigned short As[128*64];
    __shared__ __align__(16) unsigned short Bs[128*64];
    const int tid  = threadIdx.x;
    const int wave = tid >> 6, lane = tid & 63;
    const int row0 = blockIdx.y << 7, col0 = blockIdx.x << 7;
    const int wm = wave >> 1, wn = wave & 1;
    const int fr = lane & 15, fq = lane >> 4;
    f32x4 acc[4][4] = {};
    for (int k0 = 0; k0 < K; k0 += 64){
        __syncthreads();
        #pragma unroll
        for (int i = 0; i < 4; ++i){
            int chb = (wave*4 + i) * 64;
            int ch  = chb + lane;
            int r   = ch >> 3, c8 = ch & 7;
            gload16((const char*)(A  + (size_t)(row0 + r)*K + k0) + c8*16, As + chb*8);
            gload16((const char*)(Bt + (size_t)(col0 + r)*K + k0) + c8*16, Bs + chb*8);
        }
        __syncthreads();
        #pragma unroll
        for (int ks = 0; ks < 2; ++ks){
            bf16x8 av[4], bv[4];
            #pragma unroll
            for (int m = 0; m < 4; ++m)
                av[m] = *(const bf16x8*)(As + ((wm<<6)+(m<<4)+fr)*64 + (ks<<5) + (fq<<3));
            #pragma unroll
            for (int n = 0; n < 4; ++n)
                bv[n] = *(const bf16x8*)(Bs + ((wn<<6)+(n<<4)+fr)*64 + (ks<<5) + (fq<<3));
            #pragma unroll
            for (int m = 0; m < 4; ++m)
                #pragma unroll
                for (int n = 0; n < 4; ++n)
                    acc[m][n] = __builtin_amdgcn_mfma_f32_16x16x32_bf16(bv[n], av[m], acc[m][n], 0, 0, 0);
        }
    }
    #pragma unroll
    for (int m = 0; m < 4; ++m){
        int row = row0 + (wm<<6) + (m<<4) + fr;
        OutT* crow = C + (size_t)row*N + col0 + (wn<<6) + (fq<<2);
        #pragma unroll
        for (int n = 0; n < 4; ++n){
            if constexpr (sizeof(OutT) == 2){
                unsigned lo = f2bf(acc[m][n][0]) | ((unsigned)f2bf(acc[m][n][1]) << 16);
                unsigned hi = f2bf(acc[m][n][2]) | ((unsigned)f2bf(acc[m][n][3]) << 16);
                uint2 pk; pk.x = lo; pk.y = hi;
                *(uint2*)((unsigned short*)crow + (n<<4)) = pk;
            } else {
                float4 pk; pk.x = acc[m][n][0]; pk.y = acc[m][n][1];
                pk.z = acc[m][n][2]; pk.w = acc[m][n][3];
                *(float4*)((float*)crow + (n<<4)) = pk;
            }
        }
    }
}

// ---------------- 256^2 8-phase GEMM (round-5 proven; used for L2) ----------------
template<int MQ, int NQ>
__device__ __forceinline__ void mfmaq(f32x4 (&acc)[8][4], bf16x8 (&a)[4][2], bf16x8 (&b)[2][2]){
    #pragma unroll
    for (int m = 0; m < 4; ++m)
        #pragma unroll
        for (int n = 0; n < 2; ++n)
            #pragma unroll
            for (int ks = 0; ks < 2; ++ks)
                acc[MQ*4+m][NQ*2+n] = __builtin_amdgcn_mfma_f32_16x16x32_bf16(
                    b[n][ks], a[m][ks], acc[MQ*4+m][NQ*2+n], 0, 0, 0);
}

#define MIDBAR() do{ __builtin_amdgcn_s_barrier(); \
                     asm volatile("s_waitcnt lgkmcnt(0)" ::: "memory"); \
                     __builtin_amdgcn_sched_barrier(0); \
                     __builtin_amdgcn_s_setprio(1); }while(0)
#define ENDBAR() do{ __builtin_amdgcn_s_setprio(0); \
                     __builtin_amdgcn_s_barrier(); }while(0)

template<int NK>
__global__ __launch_bounds__(512, 1)
void gemm8p(const unsigned short* __restrict__ Ain0, const unsigned short* __restrict__ Btin0,
            unsigned short* __restrict__ Cout0,
            const unsigned short* __restrict__ Ain1, const unsigned short* __restrict__ Btin1,
            unsigned short* __restrict__ Cout1, int N){
    constexpr int LDK = NK*64;
    const unsigned short* A  = blockIdx.z ? Ain1 : Ain0;
    const unsigned short* Bt = blockIdx.z ? Btin1 : Btin0;
    unsigned short* C = blockIdx.z ? Cout1 : Cout0;
    __shared__ __align__(16) unsigned short lds[2][4][8192];
    const int tid = threadIdx.x, w = tid >> 6, l = tid & 63;
    const int nbx = gridDim.x;
    const int nwg = gridDim.x * gridDim.y;
    int blin = blockIdx.y * nbx + blockIdx.x;
    int sw = (blin & 7) * (nwg >> 3) + (blin >> 3);
    const int bx = sw % nbx, by = sw / nbx;
    const int row0 = by << 8, col0 = bx << 8;
    const int wm = w >> 2, wn = w & 3;
    const int fr = l & 15, fq = l >> 4;

    f32x4 acc[8][4] = {};
    bf16x8 a[4][2], b01[2][2], b23[2][2];

    const unsigned short* gA = A + (size_t)row0 * LDK;
    const unsigned short* gB = Bt + (size_t)col0 * LDK;

    auto STG = [&](const unsigned short* gbase, int t, int half, unsigned short* ldsHalf){
        #pragma unroll
        for (int s = 0; s < 2; ++s){
            int o = s*8192 + w*1024 + l*16;
            int q = o ^ ((o >> 3) & 0x70);
            int row = q >> 7;
            gload16((const char*)(gbase + (size_t)(half*128 + row)*LDK + t*64) + (q & 127),
                    ldsHalf + s*4096 + w*512);
        }
    };
    auto LDA = [&](const unsigned short* half, int rb, int ks){
        int lg = (rb*16 + fr)*128 + ks*64 + fq*16;
        int ph = lg ^ ((fr & 7) << 4);
        return *(const bf16x8*)((const char*)half + ph);
    };

    STG(gA, 0, 0, &lds[0][0][0]); STG(gA, 0, 1, &lds[0][1][0]);
    STG(gB, 0, 0, &lds[0][2][0]); STG(gB, 0, 1, &lds[0][3][0]);
    STG(gB, 1, 0, &lds[1][2][0]); STG(gB, 1, 1, &lds[1][3][0]);
    asm volatile("s_waitcnt vmcnt(4)" ::: "memory");
    __builtin_amdgcn_s_barrier();

    const unsigned short* myA[2] = { &lds[0][wm][0], &lds[1][wm][0] };
    const unsigned short* myB[2] = { &lds[0][2+(wn>>1)][0], &lds[1][2+(wn>>1)][0] };
    const int brb = (wn & 1) * 4;

    for (int i = 0; i < NK/2; ++i){
        const int t0 = 2*i, t1 = 2*i + 1;
        #pragma unroll
        for (int m = 0; m < 4; ++m){ a[m][0] = LDA(myA[0], m, 0); a[m][1] = LDA(myA[0], m, 1); }
        #pragma unroll
        for (int n = 0; n < 2; ++n){ b01[n][0] = LDA(myB[0], brb+n, 0); b01[n][1] = LDA(myB[0], brb+n, 1); }
        STG(gA, t1, 0, &lds[1][0][0]);
        MIDBAR(); mfmaq<0,0>(acc, a, b01); ENDBAR();
        #pragma unroll
        for (int n = 0; n < 2; ++n){ b23[n][0] = LDA(myB[0], brb+2+n, 0); b23[n][1] = LDA(myB[0], brb+2+n, 1); }
        STG(gA, t1, 1, &lds[1][1][0]);
        MIDBAR(); mfmaq<0,1>(acc, a, b23); ENDBAR();
        #pragma unroll
        for (int m = 0; m < 4; ++m){ a[m][0] = LDA(myA[0], 4+m, 0); a[m][1] = LDA(myA[0], 4+m, 1); }
        STG(gB, t0+2, 0, &lds[0][2][0]);
        MIDBAR(); mfmaq<1,0>(acc, a, b01); ENDBAR();
        STG(gB, t0+2, 1, &lds[0][3][0]);
        asm volatile("s_waitcnt vmcnt(4)" ::: "memory");
        MIDBAR(); mfmaq<1,1>(acc, a, b23); ENDBAR();
        #pragma unroll
        for (int m = 0; m < 4; ++m){ a[m][0] = LDA(myA[1], m, 0); a[m][1] = LDA(myA[1], m, 1); }
        #pragma unroll
        for (int n = 0; n < 2; ++n){ b01[n][0] = LDA(myB[1], brb+n, 0); b01[n][1] = LDA(myB[1], brb+n, 1); }
        STG(gA, t0+2, 0, &lds[0][0][0]);
        MIDBAR(); mfmaq<0,0>(acc, a, b01); ENDBAR();
        #pragma unroll
        for (int n = 0; n < 2; ++n){ b23[n][0] = LDA(myB[1], brb+2+n, 0); b23[n][1] = LDA(myB[1], brb+2+n, 1); }
        STG(gA, t0+2, 1, &lds[0][1][0]);
        MIDBAR(); mfmaq<0,1>(acc, a, b23); ENDBAR();
        #pragma unroll
        for (int m = 0; m < 4; ++m){ a[m][0] = LDA(myA[1], 4+m, 0); a[m][1] = LDA(myA[1], 4+m, 1); }
        STG(gB, t1+2, 0, &lds[1][2][0]);
        MIDBAR(); mfmaq<1,0>(acc, a, b01); ENDBAR();
        STG(gB, t1+2, 1, &lds[1][3][0]);
        asm volatile("s_waitcnt vmcnt(4)" ::: "memory");
        MIDBAR(); mfmaq<1,1>(acc, a, b23); ENDBAR();
    }
    asm volatile("s_waitcnt vmcnt(0)" ::: "memory");

    #pragma unroll
    for (int m = 0; m < 8; ++m){
        int row = row0 + wm*128 + m*16 + fr;
        unsigned short* crow = C + (size_t)row*N + col0 + wn*64 + fq*4;
        #pragma unroll
        for (int n = 0; n < 4; ++n){
            unsigned lo = f2bf(acc[m][n][0]) | ((unsigned)f2bf(acc[m][n][1]) << 16);
            unsigned hi = f2bf(acc[m][n][2]) | ((unsigned)f2bf(acc[m][n][3]) << 16);
            uint2 pk; pk.x = lo; pk.y = hi;
            *(uint2*)(crow + (n<<4)) = pk;
        }
    }
}

// ---------------- 128^2 double-buffered GEMM BK=32 (L1; measured 130us) ----------------
template<int NT, typename OutT>
__global__ __launch_bounds__(256, 3)
void gemm_db(const unsigned short* __restrict__ A0, const unsigned short* __restrict__ Bt0,
             OutT* __restrict__ C0,
             const unsigned short* __restrict__ A1, const unsigned short* __restrict__ Bt1,
             OutT* __restrict__ C1, int N){
    constexpr int LDK = NT*32;
    const unsigned short* A  = blockIdx.z ? A1 : A0;
    const unsigned short* Bt = blockIdx.z ? Bt1 : Bt0;
    OutT* C = blockIdx.z ? C1 : C0;
    __shared__ __align__(16) unsigned short lds[2][2][4096];
    const int tid = threadIdx.x, w = tid >> 6, l = tid & 63;
    const int wm = w >> 1, wn = w & 1;
    const int fr = l & 15, fq = l >> 4;
    const int nbx = gridDim.x;
    const int nwg = gridDim.x * gridDim.y;
    int blin = blockIdx.y * nbx + blockIdx.x;
    int sw = (blin & 7) * (nwg >> 3) + (blin >> 3);
    const int bx = sw % nbx, by = sw / nbx;
    const int row0 = by << 7, col0 = bx << 7;

    const unsigned short* gA = A + (size_t)row0 * LDK;
    const unsigned short* gB = Bt + (size_t)col0 * LDK;

    auto STG = [&](int buf, int t){
        #pragma unroll
        for (int mtx = 0; mtx < 2; ++mtx){
            const unsigned short* gb = mtx ? gB : gA;
            #pragma unroll
            for (int ld = 0; ld < 2; ++ld){
                int o = (ld*256 + tid) * 16;
                int row = o >> 6;
                int kb = (o & 63) ^ ((row & 3) << 4);
                gload16((const char*)(gb + (size_t)row*LDK + t*32) + kb,
                        (char*)&lds[buf][mtx][0] + o);
            }
        }
    };

    f32x4 acc[4][4] = {};
    STG(0, 0);
    __syncthreads();
    for (int t = 0; t < NT; ++t){
        int cur = t & 1;
        if (t + 1 < NT) STG(cur ^ 1, t + 1);
        bf16x8 av[4], bv[4];
        #pragma unroll
        for (int m = 0; m < 4; ++m){
            int r = wm*64 + m*16 + fr;
            int p = (r*64 + fq*16) ^ ((r & 3) << 4);
            av[m] = *(const bf16x8*)((const char*)&lds[cur][0][0] + p);
        }
        #pragma unroll
        for (int n = 0; n < 4; ++n){
            int r = wn*64 + n*16 + fr;
            int p = (r*64 + fq*16) ^ ((r & 3) << 4);
            bv[n] = *(const bf16x8*)((const char*)&lds[cur][1][0] + p);
        }
        #pragma unroll
        for (int m = 0; m < 4; ++m)
            #pragma unroll
            for (int n = 0; n < 4; ++n)
                acc[m][n] = __builtin_amdgcn_mfma_f32_16x16x32_bf16(bv[n], av[m], acc[m][n], 0, 0, 0);
        __syncthreads();
    }

    #pragma unroll
    for (int m = 0; m < 4; ++m){
        int row = row0 + wm*64 + m*16 + fr;
        OutT* crow = C + (size_t)row*N + col0 + (wn<<6) + (fq<<2);
        #pragma unroll
        for (int n = 0; n < 4; ++n){
            if constexpr (sizeof(OutT) == 2){
                unsigned lo = f2bf(acc[m][n][0]) | ((unsigned)f2bf(acc[m][n][1]) << 16);
                unsigned hi = f2bf(acc[m][n][2]) | ((unsigned)f2bf(acc[m][n][3]) << 16);
                uint2 pk; pk.x = lo; pk.y = hi;
                *(uint2*)((unsigned short*)crow + (n<<4)) = pk;
            } else {
                float4 pk; pk.x = acc[m][n][0]; pk.y = acc[m][n][1];
                pk.z = acc[m][n][2]; pk.w = acc[m][n][3];
                *(float4*)((float*)crow + (n<<4)) = pk;
            }
        }
    }
}

// ---------------- vectorized CSR gathers (z-merged over nets) ----------------
template<typename TO, bool RELU>
__global__ void gather8z(const int* __restrict__ rp0, const int* __restrict__ el0,
                         const unsigned short* __restrict__ t0, const float* __restrict__ b0,
                         TO* __restrict__ o0,
                         const int* __restrict__ rp1, const int* __restrict__ el1,
                         const unsigned short* __restrict__ t1, const float* __restrict__ b1,
                         TO* __restrict__ o1,
                         int tStride, int coutShift){
    const int* rowptr = blockIdx.z ? rp1 : rp0;
    const int* elist  = blockIdx.z ? el1 : el0;
    const unsigned short* t = blockIdx.z ? t1 : t0;
    const float* bias = blockIdx.z ? b1 : b0;
    TO* out = blockIdx.z ? o1 : o0;
    int idx = blockIdx.x*256 + threadIdx.x;
    int chSh = coutShift - 3;
    int d = idx >> chSh;
    int c0 = (idx & ((1 << chSh) - 1)) << 3;
    float acc[8];
    {
        const float4* bb = (const float4*)(bias + c0);
        float4 a = bb[0], b = bb[1];
        acc[0]=a.x; acc[1]=a.y; acc[2]=a.z; acc[3]=a.w;
        acc[4]=b.x; acc[5]=b.y; acc[6]=b.z; acc[7]=b.w;
    }
    int j1 = rowptr[d+1];
    #pragma unroll 2
    for (int j = rowptr[d]; j < j1; ++j){
        int p = elist[j];
        int s = p & 15, sr = p >> 4;
        bf16x8 v = *(const bf16x8*)(t + (size_t)sr*tStride + (s << coutShift) + c0);
        #pragma unroll
        for (int k = 0; k < 8; ++k) acc[k] += bf2f((unsigned short)v[k]);
    }
    if (RELU){
        #pragma unroll
        for (int k = 0; k < 8; ++k) acc[k] = fmaxf(acc[k], 0.f);
    }
    if constexpr (sizeof(TO) == 2){
        union { bf16x8 v; unsigned short u[8]; } r;
        #pragma unroll
        for (int k = 0; k < 8; ++k) r.u[k] = f2bf(acc[k]);
        *(bf16x8*)((unsigned short*)out + ((size_t)d << coutShift) + c0) = r.v;
    } else {
        float4 a = {acc[0],acc[1],acc[2],acc[3]};
        float4 b = {acc[4],acc[5],acc[6],acc[7]};
        float4* op = (float4*)((float*)out + ((size_t)d << coutShift) + c0);
        op[0] = a; op[1] = b;
    }
}

template<bool ADDV>
__global__ void gather4f(const int* __restrict__ rowptr, const int* __restrict__ elist,
                         const float* __restrict__ t,
                         const float* __restrict__ bias, const float* __restrict__ addvec,
                         float* __restrict__ out, int tStride, int coutShift){
    int idx = blockIdx.x*256 + threadIdx.x;
    int chSh = coutShift - 2;
    int d = idx >> chSh;
    int c0 = (idx & ((1 << chSh) - 1)) << 2;
    float4 bb = *(const float4*)(bias + c0);
    float acc0 = bb.x, acc1 = bb.y, acc2 = bb.z, acc3 = bb.w;
    if (ADDV){
        float4 av = *(const float4*)(addvec + c0);
        acc0 += av.x*(1.f/NN); acc1 += av.y*(1.f/NN);
        acc2 += av.z*(1.f/NN); acc3 += av.w*(1.f/NN);
    }
    int j1 = rowptr[d+1];
    #pragma unroll 2
    for (int j = rowptr[d]; j < j1; ++j){
        int sr = elist[j];
        float4 v = *(const float4*)(t + (size_t)sr*tStride + c0);
        acc0 += v.x; acc1 += v.y; acc2 += v.z; acc3 += v.w;
    }
    float4 r = {acc0, acc1, acc2, acc3};
    *(float4*)(out + ((size_t)d << coutShift) + c0) = r;
}

// ---------------- gram / fc (z-merged), mm32, tf ----------------
__global__ void gram2(const float* __restrict__ h0, float* __restrict__ g0,
                      const float* __restrict__ h1, float* __restrict__ g1){
    const float* h = blockIdx.z ? h1 : h0;
    float* g = blockIdx.z ? g1 : g0;
    const int RPB = NN/64;
    int r0 = blockIdx.x*RPB;
    int i = threadIdx.x >> 5, j = threadIdx.x & 31;
    float s = 0.f;
    for (int r = 0; r < RPB; ++r){
        const float* row = h + (size_t)(r0+r)*32;
        s += row[i]*row[j];
    }
    atomicAdd(&g[threadIdx.x], s);
}

__global__ void fc2(const float* __restrict__ g0, const float* __restrict__ fcW0,
                    const float* __restrict__ fcb0, float* __restrict__ o0,
                    const float* __restrict__ g1, const float* __restrict__ fcW1,
                    const float* __restrict__ fcb1, float* __restrict__ o1){
    const float* g   = blockIdx.z ? g1 : g0;
    const float* fcW = blockIdx.z ? fcW1 : fcW0;
    const float* fcb = blockIdx.z ? fcb1 : fcb0;
    float* outMat    = blockIdx.z ? o1 : o0;
    int i = blockIdx.x;
    float s = 0.f;
    for (int j = threadIdx.x; j < 1024; j += 256)
        s += g[j] * (1.f/NN) * fcW[(size_t)i*1024 + j];
    __shared__ float red[256];
    red[threadIdx.x] = s; __syncthreads();
    for (int off = 128; off > 0; off >>= 1){
        if (threadIdx.x < off) red[threadIdx.x] += red[threadIdx.x+off];
        __syncthreads();
    }
    if (threadIdx.x == 0) outMat[i] = red[0] + fcb[i];
}

__global__ void mm32_kernel(const float* __restrict__ A, const float* __restrict__ B,
                            float* __restrict__ T){
    int i = threadIdx.x >> 5, j = threadIdx.x & 31;
    float s = 0.f;
    for (int k = 0; k < 32; ++k) s += A[i*32+k]*B[k*32+j];
    T[threadIdx.x] = s;
}

__global__ void tf_cvt_kernel(const float* __restrict__ cc, const float* __restrict__ T,
                              unsigned short* __restrict__ tfbB){
    __shared__ float Ts[1024];
    for (int i = threadIdx.x; i < 1024; i += blockDim.x) Ts[i] = T[i];
    __syncthreads();
    int idx = blockIdx.x*blockDim.x + threadIdx.x;
    int n = idx >> 5, i = idx & 31;
    float s = 0.f;
    const float* crow = cc + (size_t)n*32;
    #pragma unroll
    for (int j = 0; j < 32; ++j) s += crow[j] * Ts[i*32+j];
    tfbB[(size_t)n*64 + i] = f2bf(s);
    tfbB[(size_t)n*64 + 32 + i] = 0;
}

extern "C" void kernel_launch(void* const* d_in, const int* in_sizes, int n_in,
                              void* d_out, int out_size, void* d_ws, size_t ws_size,
                              hipStream_t stream){
    const float* cF   = (const float*)d_in[0];
    const float* sF   = (const float*)d_in[1];
    const int*   cEI  = (const int*)d_in[2];
    const int*   cSel = (const int*)d_in[3];
    const int*   sEI  = (const int*)d_in[4];
    const int*   sSel = (const int*)d_in[5];
    const float* compW= (const float*)d_in[6];
    const float* compB= (const float*)d_in[7];
    const float* unzW = (const float*)d_in[8];
    const float* unzB = (const float*)d_in[9];
    const float* cW1=(const float*)d_in[10]; const float* cB1=(const float*)d_in[11];
    const float* cW2=(const float*)d_in[12]; const float* cB2=(const float*)d_in[13];
    const float* cW3=(const float*)d_in[14]; const float* cB3=(const float*)d_in[15];
    const float* cFW=(const float*)d_in[16]; const float* cFB=(const float*)d_in[17];
    const float* sW1=(const float*)d_in[18]; const float* sB1=(const float*)d_in[19];
    const float* sW2=(const float*)d_in[20]; const float* sB2=(const float*)d_in[21];
    const float* sW3=(const float*)d_in[22]; const float* sB3=(const float*)d_in[23];
    const float* sFW=(const float*)d_in[24]; const float* sFB=(const float*)d_in[25];

    float* out  = (float*)d_out;
    float* Tmat = out + (size_t)NN*CC;

    // ---- workspace carve (~193 MB) ----
    char* w = (char*)d_ws;
    auto alloc = [&](size_t b)->char*{ char* p = w; w += (b + 255) & ~(size_t)255; return p; };
    float* cCol = (float*)alloc(512*4);
    float* sCol = (float*)alloc(512*4);
    float* cg   = (float*)alloc(1024*4);
    float* sg   = (float*)alloc(1024*4);
    float* cMat = (float*)alloc(1024*4);
    float* sMat = (float*)alloc(1024*4);
    int* cCnt = (int*)alloc(NN*4);
    int* cCur = (int*)alloc(NN*4);
    int* sCnt = (int*)alloc(NN*4);
    int* sCur = (int*)alloc(NN*4);
    int* cCnt0= (int*)alloc(NN*4);
    int* cCur0= (int*)alloc(NN*4);
    int* cRow = (int*)alloc((NN+1)*4);
    int* sRow = (int*)alloc((NN+1)*4);
    int* cRow0= (int*)alloc((NN+1)*4);
    int* cEl  = (int*)alloc(EE*4);
    int* sEl  = (int*)alloc(EE*4);
    int* cEl0 = (int*)alloc(EE*4);
    float* ccbuf = (float*)alloc((size_t)NN*32*4);
    unsigned short* tfbB = (unsigned short*)alloc((size_t)NN*64*2);
    unsigned short* wtC1 = (unsigned short*)alloc((size_t)2304*512*2);
    unsigned short* wtC2 = (unsigned short*)alloc((size_t)1280*256*2);
    unsigned short* wtC3 = (unsigned short*)alloc((size_t)384*128*2);
    unsigned short* wtS1 = (unsigned short*)alloc((size_t)2304*512*2);
    unsigned short* wtS2 = (unsigned short*)alloc((size_t)1280*256*2);
    unsigned short* wtS3 = (unsigned short*)alloc((size_t)384*128*2);
    unsigned short* wtCo = (unsigned short*)alloc((size_t)128*512*2);
    unsigned short* wtU  = (unsigned short*)alloc((size_t)512*64*2);
    unsigned short* cFcB = (unsigned short*)alloc((size_t)NN*512*2);
    unsigned short* sFcB = (unsigned short*)alloc((size_t)NN*512*2);
    float* h3c = (float*)alloc((size_t)NN*32*4);
    float* h3s = (float*)alloc((size_t)NN*32*4);
    unsigned short* tC = (unsigned short*)alloc((size_t)NN*2304*2);
    unsigned short* tS = (unsigned short*)alloc((size_t)NN*2304*2);
    float* tFc = (float*)tC;
    unsigned short* h1c = cFcB;
    unsigned short* h1s = sFcB;
    unsigned short* h2c = cFcB + (size_t)NN*256;
    unsigned short* h2s = sFcB + (size_t)NN*256;

    const int* cSrc = cEI; const int* cDst = cEI + EE;
    const int* sSrc = sEI; const int* sDst = sEI + EE;

    // ---- zero the contiguous accumulator block ----
    int zeroInts = (int)(((char*)cCur0 - (char*)d_ws)/4) + NN;
    zero_i<<<idiv(zeroInts,256),256,0,stream>>>((int*)d_ws, zeroInts);

    // ---- means + centering (bf16 out) ----
    colsum2<<<dim3(256,1,2),128,0,stream>>>(cF, cCol, sF, sCol);
    center2<<<dim3(NN*CC/1024,1,2),256,0,stream>>>(cF, cCol, (ushort4*)cFcB,
                                                   sF, sCol, (ushort4*)sFcB);

    // ---- weight transposes ----
    wtrans2z<<<dim3(2,16,18),128,0,stream>>>(cW1, sW1, wtC1, wtS1, 512, 256);
    wtrans2z<<<dim3(1,8,18),128,0,stream>>>(cW2, sW2, wtC2, wtS2, 256, 128);
    wtransz<<<dim3(idiv(384*128,256),1,2),256,0,stream>>>(cW3, wtC3, sW3, wtS3, 9,128,32, 384,128);
    wtransz<<<dim3(idiv(128*512,256),1,1),256,0,stream>>>(compW, wtCo, compW, wtCo, 1,512,32, 128,512);
    wtransz<<<dim3(idiv(512*64,256),1,1),256,0,stream>>>(unzW, wtU, unzW, wtU, 1,32,512, 512,64);

    // ---- CSR build (merged) ----
    csr_count3<<<dim3(idiv(EE,256),1,3),256,0,stream>>>(cDst, sDst, cSel, cCnt, sCnt, cCnt0);
    csr_scan3<<<dim3(1,1,3),1024,0,stream>>>(cCnt, sCnt, cCnt0, cRow, sRow, cRow0);
    csr_fill3<<<dim3(idiv(EE,256),1,3),256,0,stream>>>(cSrc,cDst,cSel, sSrc,sDst,sSel,
                                                       cRow,sRow,cRow0, cCur,sCur,cCur0,
                                                       cEl,sEl,cEl0);

    // ---- compress: tF = cFc@compW ; cc = bias + gather(sel==0) ----
    mfma_gemm<float><<<dim3(1,128,1),256,0,stream>>>(cFcB, wtCo, tFc,
                                                     cFcB, wtCo, tFc, 512, 128);
    gather4f<false><<<NN*8/256,256,0,stream>>>(cRow0,cEl0,tFc,compB,nullptr,ccbuf,128,5);

    // ---- L1 (both nets): gemm_db (measured 130us vs gemm8p 144us) ----
    gemm_db<16,unsigned short><<<dim3(18,128,2),256,0,stream>>>(cFcB, wtC1, tC,
                                                                sFcB, wtS1, tS, 2304);
    gather8z<unsigned short,true><<<dim3(2048,1,2),256,0,stream>>>(
        cRow,cEl,tC,cB1,h1c, sRow,sEl,tS,sB1,h1s, 2304, 8);
    // ---- L2 (both nets): round-5 gemm8p ----
    gemm8p<4><<<dim3(5,64,2),512,0,stream>>>(h1c, wtC2, tC, h1s, wtS2, tS, 1280);
    gather8z<unsigned short,true><<<dim3(1024,1,2),256,0,stream>>>(
        cRow,cEl,tC,cB2,h2c, sRow,sEl,tS,sB2,h2s, 1280, 7);
    // ---- L3 (both nets): round-5 mfma_gemm ----
    mfma_gemm<unsigned short><<<dim3(3,128,2),256,0,stream>>>(h2c, wtC3, tC,
                                                              h2s, wtS3, tS, 128, 384);
    gather8z<float,false><<<dim3(256,1,2),256,0,stream>>>(
        cRow,cEl,tC,cB3,h3c, sRow,sEl,tS,sB3,h3s, 384, 5);
    // ---- gram + fc (both nets) ----
    gram2<<<dim3(64,1,2),1024,0,stream>>>(h3c, cg, h3s, sg);
    fc2<<<dim3(1024,1,2),256,0,stream>>>(cg,cFW,cFB,cMat, sg,sFW,sFB,sMat);

    // ---- transmatrix + transfeature ----
    mm32_kernel<<<1,1024,0,stream>>>(sMat, cMat, Tmat);
    tf_cvt_kernel<<<NN*32/256,256,0,stream>>>(ccbuf, Tmat, tfbB);

    // ---- unzip: out = unzip_b + sMean + gather(sel==0) of tf @ unzip_W ----
    mfma_gemm<float><<<dim3(4,128,1),256,0,stream>>>(tfbB, wtU, tFc,
                                                     tfbB, wtU, tFc, 64, 512);
    gather4f<true><<<NN*128/256,256,0,stream>>>(cRow0,cEl0,tFc,unzB,sCol,out,512,9);
}

// Round 9
// 407.907 us; speedup vs baseline: 1.5308x; 1.0312x over previous
//
#include <hip/hip_runtime.h>
#include <hip/hip_bf16.h>
#include <cstddef>
#include <cstdint>

#define NN 16384
#define EE (9*NN)
#define CC 512

typedef __attribute__((ext_vector_type(4))) float f32x4;
typedef __attribute__((ext_vector_type(8))) short bf16x8;

static inline int idiv(int a, int b){ return (a+b-1)/b; }

__device__ __forceinline__ float bf2f(unsigned short u){
    union{unsigned u; float f;} v; v.u = ((unsigned)u) << 16; return v.f;
}
__device__ __forceinline__ unsigned short f2bf(float f){
    union{float f; unsigned u;} v; v.f = f;
    unsigned r = v.u + 0x7fffu + ((v.u >> 16) & 1u);
    return (unsigned short)(r >> 16);
}

__device__ __forceinline__ void gload16(const void* gsrc, void* ldst){
    __builtin_amdgcn_global_load_lds(
        (const __attribute__((address_space(1))) unsigned int*)gsrc,
        (__attribute__((address_space(3))) unsigned int*)ldst,
        16, 0, 0);
}

// ---------------- utility kernels ----------------

__global__ void zero_i(int* __restrict__ p, int n){
    int i = blockIdx.x*256 + threadIdx.x; if (i < n) p[i] = 0;
}

// z-merged column sums of F[NN][CC] via float4; cs pre-zeroed.
__global__ void colsum2(const float* __restrict__ F0, float* __restrict__ cs0,
                        const float* __restrict__ F1, float* __restrict__ cs1){
    const float* F = blockIdx.z ? F1 : F0;
    float* cs = blockIdx.z ? cs1 : cs0;
    const int RPB = NN/256;
    int r0 = blockIdx.x * RPB;
    int c4 = threadIdx.x;
    float4 s = {0.f,0.f,0.f,0.f};
    for (int r = 0; r < RPB; ++r){
        float4 v = ((const float4*)(F + (size_t)(r0+r)*CC))[c4];
        s.x += v.x; s.y += v.y; s.z += v.z; s.w += v.w;
    }
    atomicAdd(&cs[c4*4+0], s.x);
    atomicAdd(&cs[c4*4+1], s.y);
    atomicAdd(&cs[c4*4+2], s.z);
    atomicAdd(&cs[c4*4+3], s.w);
}

__global__ void center2(const float* __restrict__ F0, const float* __restrict__ cs0,
                        ushort4* __restrict__ o0,
                        const float* __restrict__ F1, const float* __restrict__ cs1,
                        ushort4* __restrict__ o1){
    const float* F = blockIdx.z ? F1 : F0;
    const float* cs = blockIdx.z ? cs1 : cs0;
    ushort4* o = blockIdx.z ? o1 : o0;
    int i = blockIdx.x*256 + threadIdx.x;
    float4 v = ((const float4*)F)[i];
    int c = (i << 2) & (CC-1);
    float4 m = *(const float4*)(cs + c);
    ushort4 r;
    r.x = f2bf(v.x - m.x*(1.f/NN));
    r.y = f2bf(v.y - m.y*(1.f/NN));
    r.z = f2bf(v.z - m.z*(1.f/NN));
    r.w = f2bf(v.w - m.w*(1.f/NN));
    o[i] = r;
}

// generic weight transpose (small weights), z-selectable pair
__global__ void wtransz(const float* __restrict__ W0, unsigned short* __restrict__ Wt0,
                        const float* __restrict__ W1, unsigned short* __restrict__ Wt1,
                        int S, int K, int Cout, int Npad, int Kpad){
    const float* W = blockIdx.z ? W1 : W0;
    unsigned short* Wt = blockIdx.z ? Wt1 : Wt0;
    int idx = blockIdx.x*256 + threadIdx.x;
    if (idx >= Npad*Kpad) return;
    int colp = idx / Kpad, k = idx - colp*Kpad;
    int s = colp / Cout, j = colp - s*Cout;
    float v = 0.f;
    if (s < S && k < K) v = W[((size_t)s*K + k)*Cout + j];
    Wt[idx] = f2bf(v);
}

// fast LDS-tiled transpose, z-merged over 2 nets x 9 selections
__global__ void wtrans2z(const float* __restrict__ W0, const float* __restrict__ W1,
                         unsigned short* __restrict__ Wt0, unsigned short* __restrict__ Wt1,
                         int K, int Cout){
    __shared__ float tile[32][129];
    int s = blockIdx.z % 9;
    const float* W = (blockIdx.z < 9) ? W0 : W1;
    unsigned short* Wt = (blockIdx.z < 9) ? Wt0 : Wt1;
    int jb = blockIdx.x*128, kb = blockIdx.y*32;
    const float* Ws = W + (size_t)s*K*Cout;
    for (int r = 0; r < 32; ++r)
        tile[r][threadIdx.x] = Ws[(size_t)(kb+r)*Cout + jb + threadIdx.x];
    __syncthreads();
    int kk = threadIdx.x & 31, j0 = threadIdx.x >> 5;
    for (int jj = j0; jj < 128; jj += 4)
        Wt[(size_t)(s*Cout + jb + jj)*K + kb + kk] = f2bf(tile[kk][jj]);
}

// ---------------- CSR build (z-merged) ----------------
__global__ void csr_count3(const int* __restrict__ cDst, const int* __restrict__ sDst,
                           const int* __restrict__ cSel,
                           int* __restrict__ cCnt, int* __restrict__ sCnt, int* __restrict__ cCnt0){
    int e = blockIdx.x*256 + threadIdx.x;
    if (e >= EE) return;
    int z = blockIdx.z;
    if (z == 0)      atomicAdd(&cCnt[cDst[e]], 1);
    else if (z == 1) atomicAdd(&sCnt[sDst[e]], 1);
    else if (cSel[e] == 0) atomicAdd(&cCnt0[cDst[e]], 1);
}
__global__ void csr_scan3(const int* __restrict__ c0, const int* __restrict__ c1,
                          const int* __restrict__ c2,
                          int* __restrict__ r0, int* __restrict__ r1, int* __restrict__ r2){
    const int* cnt = blockIdx.z==0 ? c0 : (blockIdx.z==1 ? c1 : c2);
    int* rowptr    = blockIdx.z==0 ? r0 : (blockIdx.z==1 ? r1 : r2);
    __shared__ int part[1024];
    int t = threadIdx.x;
    int base = t*16, s = 0;
    int local[16];
    #pragma unroll
    for (int i = 0; i < 16; ++i){ local[i] = s; s += cnt[base+i]; }
    part[t] = s; __syncthreads();
    for (int off = 1; off < 1024; off <<= 1){
        int v = (t >= off) ? part[t-off] : 0;
        __syncthreads();
        part[t] += v;
        __syncthreads();
    }
    int pre = (t == 0) ? 0 : part[t-1];
    #pragma unroll
    for (int i = 0; i < 16; ++i) rowptr[base+i] = pre + local[i];
    if (t == 1023) rowptr[NN] = part[1023];
}
__global__ void csr_fill3(const int* __restrict__ cSrc, const int* __restrict__ cDst,
                          const int* __restrict__ cSel,
                          const int* __restrict__ sSrc, const int* __restrict__ sDst,
                          const int* __restrict__ sSel,
                          const int* __restrict__ cRow, const int* __restrict__ sRow,
                          const int* __restrict__ cRow0,
                          int* __restrict__ cCur, int* __restrict__ sCur, int* __restrict__ cCur0,
                          int* __restrict__ cEl, int* __restrict__ sEl, int* __restrict__ cEl0){
    int e = blockIdx.x*256 + threadIdx.x;
    if (e >= EE) return;
    int z = blockIdx.z;
    if (z == 0){
        int d = cDst[e];
        int p = atomicAdd(&cCur[d], 1);
        cEl[cRow[d] + p] = (cSrc[e] << 4) | cSel[e];
    } else if (z == 1){
        int d = sDst[e];
        int p = atomicAdd(&sCur[d], 1);
        sEl[sRow[d] + p] = (sSrc[e] << 4) | sSel[e];
    } else if (cSel[e] == 0){
        int d = cDst[e];
        int p = atomicAdd(&cCur0[d], 1);
        cEl0[cRow0[d] + p] = cSrc[e];
    }
}

// ---------------- 128^2 MFMA GEMM (2-phase BK=64; proven round 5), z-selectable ----------------
template<typename OutT>
__global__ __launch_bounds__(256, 2)
void mfma_gemm(const unsigned short* __restrict__ A0, const unsigned short* __restrict__ Bt0,
               OutT* __restrict__ C0,
               const unsigned short* __restrict__ A1, const unsigned short* __restrict__ Bt1,
               OutT* __restrict__ C1, int K, int N){
    const unsigned short* A  = blockIdx.z ? A1 : A0;
    const unsigned short* Bt = blockIdx.z ? Bt1 : Bt0;
    OutT* C = blockIdx.z ? C1 : C0;
    __shared__ __align__(16) unsigned short As[128*64];
    __shared__ __align__(16) unsigned short Bs[128*64];
    const int tid  = threadIdx.x;
    const int wave = tid >> 6, lane = tid & 63;
    const int row0 = blockIdx.y << 7, col0 = blockIdx.x << 7;
    const int wm = wave >> 1, wn = wave & 1;
    const int fr = lane & 15, fq = lane >> 4;
    f32x4 acc[4][4] = {};
    for (int k0 = 0; k0 < K; k0 += 64){
        __syncthreads();
        #pragma unroll
        for (int i = 0; i < 4; ++i){
            int chb = (wave*4 + i) * 64;
            int ch  = chb + lane;
            int r   = ch >> 3, c8 = ch & 7;
            gload16((const char*)(A  + (size_t)(row0 + r)*K + k0) + c8*16, As + chb*8);
            gload16((const char*)(Bt + (size_t)(col0 + r)*K + k0) + c8*16, Bs + chb*8);
        }
        __syncthreads();
        #pragma unroll
        for (int ks = 0; ks < 2; ++ks){
            bf16x8 av[4], bv[4];
            #pragma unroll
            for (int m = 0; m < 4; ++m)
                av[m] = *(const bf16x8*)(As + ((wm<<6)+(m<<4)+fr)*64 + (ks<<5) + (fq<<3));
            #pragma unroll
            for (int n = 0; n < 4; ++n)
                bv[n] = *(const bf16x8*)(Bs + ((wn<<6)+(n<<4)+fr)*64 + (ks<<5) + (fq<<3));
            #pragma unroll
            for (int m = 0; m < 4; ++m)
                #pragma unroll
                for (int n = 0; n < 4; ++n)
                    acc[m][n] = __builtin_amdgcn_mfma_f32_16x16x32_bf16(bv[n], av[m], acc[m][n], 0, 0, 0);
        }
    }
    #pragma unroll
    for (int m = 0; m < 4; ++m){
        int row = row0 + (wm<<6) + (m<<4) + fr;
        OutT* crow = C + (size_t)row*N + col0 + (wn<<6) + (fq<<2);
        #pragma unroll
        for (int n = 0; n < 4; ++n){
            if constexpr (sizeof(OutT) == 2){
                unsigned lo = f2bf(acc[m][n][0]) | ((unsigned)f2bf(acc[m][n][1]) << 16);
                unsigned hi = f2bf(acc[m][n][2]) | ((unsigned)f2bf(acc[m][n][3]) << 16);
                uint2 pk; pk.x = lo; pk.y = hi;
                *(uint2*)((unsigned short*)crow + (n<<4)) = pk;
            } else {
                float4 pk; pk.x = acc[m][n][0]; pk.y = acc[m][n][1];
                pk.z = acc[m][n][2]; pk.w = acc[m][n][3];
                *(float4*)((float*)crow + (n<<4)) = pk;
            }
        }
    }
}

// ---------------- 128^2 double-buffered GEMM BK=32, conflict-free swizzle, 4 blk/CU ----------------
// swizzle: byte ^= (((byte>>7)&3)<<4)  — mask bits 4-5 from bits 7-8 (disjoint -> involution).
// bank group per 16-lane fragment read: (r%2)*16 + (fq^((r>>1)&3))*4 -> 8 groups, 2 lanes/bank = free.
template<int NT, typename OutT>
__global__ __launch_bounds__(256, 4)
void gemm_db(const unsigned short* __restrict__ A0, const unsigned short* __restrict__ Bt0,
             OutT* __restrict__ C0,
             const unsigned short* __restrict__ A1, const unsigned short* __restrict__ Bt1,
             OutT* __restrict__ C1, int N){
    constexpr int LDK = NT*32;
    const unsigned short* A  = blockIdx.z ? A1 : A0;
    const unsigned short* Bt = blockIdx.z ? Bt1 : Bt0;
    OutT* C = blockIdx.z ? C1 : C0;
    __shared__ __align__(16) unsigned short lds[2][2][4096];
    const int tid = threadIdx.x, w = tid >> 6, l = tid & 63;
    const int wm = w >> 1, wn = w & 1;
    const int fr = l & 15, fq = l >> 4;
    const int nbx = gridDim.x;
    const int nwg = gridDim.x * gridDim.y;
    int blin = blockIdx.y * nbx + blockIdx.x;
    int sw = (blin & 7) * (nwg >> 3) + (blin >> 3);
    const int bx = sw % nbx, by = sw / nbx;
    const int row0 = by << 7, col0 = bx << 7;

    const unsigned short* gA = A + (size_t)row0 * LDK;
    const unsigned short* gB = Bt + (size_t)col0 * LDK;

    auto STG = [&](int buf, int t){
        #pragma unroll
        for (int mtx = 0; mtx < 2; ++mtx){
            const unsigned short* gb = mtx ? gB : gA;
            #pragma unroll
            for (int ld = 0; ld < 2; ++ld){
                int o = (ld*256 + tid) * 16;
                int row = o >> 6;
                int kb = (o & 63) ^ (((o >> 7) & 3) << 4);
                gload16((const char*)(gb + (size_t)row*LDK + t*32) + kb,
                        (char*)&lds[buf][mtx][0] + o);
            }
        }
    };

    f32x4 acc[4][4] = {};
    STG(0, 0);
    __syncthreads();
    for (int t = 0; t < NT; ++t){
        int cur = t & 1;
        if (t + 1 < NT) STG(cur ^ 1, t + 1);
        bf16x8 av[4], bv[4];
        #pragma unroll
        for (int m = 0; m < 4; ++m){
            int r = wm*64 + m*16 + fr;
            int p = (r*64 + fq*16) ^ (((r >> 1) & 3) << 4);
            av[m] = *(const bf16x8*)((const char*)&lds[cur][0][0] + p);
        }
        #pragma unroll
        for (int n = 0; n < 4; ++n){
            int r = wn*64 + n*16 + fr;
            int p = (r*64 + fq*16) ^ (((r >> 1) & 3) << 4);
            bv[n] = *(const bf16x8*)((const char*)&lds[cur][1][0] + p);
        }
        #pragma unroll
        for (int m = 0; m < 4; ++m)
            #pragma unroll
            for (int n = 0; n < 4; ++n)
                acc[m][n] = __builtin_amdgcn_mfma_f32_16x16x32_bf16(bv[n], av[m], acc[m][n], 0, 0, 0);
        __syncthreads();
    }

    #pragma unroll
    for (int m = 0; m < 4; ++m){
        int row = row0 + wm*64 + m*16 + fr;
        OutT* crow = C + (size_t)row*N + col0 + (wn<<6) + (fq<<2);
        #pragma unroll
        for (int n = 0; n < 4; ++n){
            if constexpr (sizeof(OutT) == 2){
                unsigned lo = f2bf(acc[m][n][0]) | ((unsigned)f2bf(acc[m][n][1]) << 16);
                unsigned hi = f2bf(acc[m][n][2]) | ((unsigned)f2bf(acc[m][n][3]) << 16);
                uint2 pk; pk.x = lo; pk.y = hi;
                *(uint2*)((unsigned short*)crow + (n<<4)) = pk;
            } else {
                float4 pk; pk.x = acc[m][n][0]; pk.y = acc[m][n][1];
                pk.z = acc[m][n][2]; pk.w = acc[m][n][3];
                *(float4*)((float*)crow + (n<<4)) = pk;
            }
        }
    }
}

// ---------------- vectorized CSR gathers (z-merged over nets) ----------------
template<typename TO, bool RELU>
__global__ void gather8z(const int* __restrict__ rp0, const int* __restrict__ el0,
                         const unsigned short* __restrict__ t0, const float* __restrict__ b0,
                         TO* __restrict__ o0,
                         const int* __restrict__ rp1, const int* __restrict__ el1,
                         const unsigned short* __restrict__ t1, const float* __restrict__ b1,
                         TO* __restrict__ o1,
                         int tStride, int coutShift){
    const int* rowptr = blockIdx.z ? rp1 : rp0;
    const int* elist  = blockIdx.z ? el1 : el0;
    const unsigned short* t = blockIdx.z ? t1 : t0;
    const float* bias = blockIdx.z ? b1 : b0;
    TO* out = blockIdx.z ? o1 : o0;
    int idx = blockIdx.x*256 + threadIdx.x;
    int chSh = coutShift - 3;
    int d = idx >> chSh;
    int c0 = (idx & ((1 << chSh) - 1)) << 3;
    float acc[8];
    {
        const float4* bb = (const float4*)(bias + c0);
        float4 a = bb[0], b = bb[1];
        acc[0]=a.x; acc[1]=a.y; acc[2]=a.z; acc[3]=a.w;
        acc[4]=b.x; acc[5]=b.y; acc[6]=b.z; acc[7]=b.w;
    }
    int j1 = rowptr[d+1];
    #pragma unroll 2
    for (int j = rowptr[d]; j < j1; ++j){
        int p = elist[j];
        int s = p & 15, sr = p >> 4;
        bf16x8 v = *(const bf16x8*)(t + (size_t)sr*tStride + (s << coutShift) + c0);
        #pragma unroll
        for (int k = 0; k < 8; ++k) acc[k] += bf2f((unsigned short)v[k]);
    }
    if (RELU){
        #pragma unroll
        for (int k = 0; k < 8; ++k) acc[k] = fmaxf(acc[k], 0.f);
    }
    if constexpr (sizeof(TO) == 2){
        union { bf16x8 v; unsigned short u[8]; } r;
        #pragma unroll
        for (int k = 0; k < 8; ++k) r.u[k] = f2bf(acc[k]);
        *(bf16x8*)((unsigned short*)out + ((size_t)d << coutShift) + c0) = r.v;
    } else {
        float4 a = {acc[0],acc[1],acc[2],acc[3]};
        float4 b = {acc[4],acc[5],acc[6],acc[7]};
        float4* op = (float4*)((float*)out + ((size_t)d << coutShift) + c0);
        op[0] = a; op[1] = b;
    }
}

template<bool ADDV>
__global__ void gather4f(const int* __restrict__ rowptr, const int* __restrict__ elist,
                         const float* __restrict__ t,
                         const float* __restrict__ bias, const float* __restrict__ addvec,
                         float* __restrict__ out, int tStride, int coutShift){
    int idx = blockIdx.x*256 + threadIdx.x;
    int chSh = coutShift - 2;
    int d = idx >> chSh;
    int c0 = (idx & ((1 << chSh) - 1)) << 2;
    float4 bb = *(const float4*)(bias + c0);
    float acc0 = bb.x, acc1 = bb.y, acc2 = bb.z, acc3 = bb.w;
    if (ADDV){
        float4 av = *(const float4*)(addvec + c0);
        acc0 += av.x*(1.f/NN); acc1 += av.y*(1.f/NN);
        acc2 += av.z*(1.f/NN); acc3 += av.w*(1.f/NN);
    }
    int j1 = rowptr[d+1];
    #pragma unroll 2
    for (int j = rowptr[d]; j < j1; ++j){
        int sr = elist[j];
        float4 v = *(const float4*)(t + (size_t)sr*tStride + c0);
        acc0 += v.x; acc1 += v.y; acc2 += v.z; acc3 += v.w;
    }
    float4 r = {acc0, acc1, acc2, acc3};
    *(float4*)(out + ((size_t)d << coutShift) + c0) = r;
}

// ---------------- gram / fc (z-merged), mm32, tf ----------------
__global__ void gram2(const float* __restrict__ h0, float* __restrict__ g0,
                      const float* __restrict__ h1, float* __restrict__ g1){
    const float* h = blockIdx.z ? h1 : h0;
    float* g = blockIdx.z ? g1 : g0;
    const int RPB = NN/64;
    int r0 = blockIdx.x*RPB;
    int i = threadIdx.x >> 5, j = threadIdx.x & 31;
    float s = 0.f;
    for (int r = 0; r < RPB; ++r){
        const float* row = h + (size_t)(r0+r)*32;
        s += row[i]*row[j];
    }
    atomicAdd(&g[threadIdx.x], s);
}

__global__ void fc2(const float* __restrict__ g0, const float* __restrict__ fcW0,
                    const float* __restrict__ fcb0, float* __restrict__ o0,
                    const float* __restrict__ g1, const float* __restrict__ fcW1,
                    const float* __restrict__ fcb1, float* __restrict__ o1){
    const float* g   = blockIdx.z ? g1 : g0;
    const float* fcW = blockIdx.z ? fcW1 : fcW0;
    const float* fcb = blockIdx.z ? fcb1 : fcb0;
    float* outMat    = blockIdx.z ? o1 : o0;
    int i = blockIdx.x;
    float s = 0.f;
    for (int j = threadIdx.x; j < 1024; j += 256)
        s += g[j] * (1.f/NN) * fcW[(size_t)i*1024 + j];
    __shared__ float red[256];
    red[threadIdx.x] = s; __syncthreads();
    for (int off = 128; off > 0; off >>= 1){
        if (threadIdx.x < off) red[threadIdx.x] += red[threadIdx.x+off];
        __syncthreads();
    }
    if (threadIdx.x == 0) outMat[i] = red[0] + fcb[i];
}

__global__ void mm32_kernel(const float* __restrict__ A, const float* __restrict__ B,
                            float* __restrict__ T){
    int i = threadIdx.x >> 5, j = threadIdx.x & 31;
    float s = 0.f;
    for (int k = 0; k < 32; ++k) s += A[i*32+k]*B[k*32+j];
    T[threadIdx.x] = s;
}

__global__ void tf_cvt_kernel(const float* __restrict__ cc, const float* __restrict__ T,
                              unsigned short* __restrict__ tfbB){
    __shared__ float Ts[1024];
    for (int i = threadIdx.x; i < 1024; i += blockDim.x) Ts[i] = T[i];
    __syncthreads();
    int idx = blockIdx.x*blockDim.x + threadIdx.x;
    int n = idx >> 5, i = idx & 31;
    float s = 0.f;
    const float* crow = cc + (size_t)n*32;
    #pragma unroll
    for (int j = 0; j < 32; ++j) s += crow[j] * Ts[i*32+j];
    tfbB[(size_t)n*64 + i] = f2bf(s);
    tfbB[(size_t)n*64 + 32 + i] = 0;
}

extern "C" void kernel_launch(void* const* d_in, const int* in_sizes, int n_in,
                              void* d_out, int out_size, void* d_ws, size_t ws_size,
                              hipStream_t stream){
    const float* cF   = (const float*)d_in[0];
    const float* sF   = (const float*)d_in[1];
    const int*   cEI  = (const int*)d_in[2];
    const int*   cSel = (const int*)d_in[3];
    const int*   sEI  = (const int*)d_in[4];
    const int*   sSel = (const int*)d_in[5];
    const float* compW= (const float*)d_in[6];
    const float* compB= (const float*)d_in[7];
    const float* unzW = (const float*)d_in[8];
    const float* unzB = (const float*)d_in[9];
    const float* cW1=(const float*)d_in[10]; const float* cB1=(const float*)d_in[11];
    const float* cW2=(const float*)d_in[12]; const float* cB2=(const float*)d_in[13];
    const float* cW3=(const float*)d_in[14]; const float* cB3=(const float*)d_in[15];
    const float* cFW=(const float*)d_in[16]; const float* cFB=(const float*)d_in[17];
    const float* sW1=(const float*)d_in[18]; const float* sB1=(const float*)d_in[19];
    const float* sW2=(const float*)d_in[20]; const float* sB2=(const float*)d_in[21];
    const float* sW3=(const float*)d_in[22]; const float* sB3=(const float*)d_in[23];
    const float* sFW=(const float*)d_in[24]; const float* sFB=(const float*)d_in[25];

    float* out  = (float*)d_out;
    float* Tmat = out + (size_t)NN*CC;

    // ---- workspace carve (~193 MB) ----
    char* w = (char*)d_ws;
    auto alloc = [&](size_t b)->char*{ char* p = w; w += (b + 255) & ~(size_t)255; return p; };
    float* cCol = (float*)alloc(512*4);
    float* sCol = (float*)alloc(512*4);
    float* cg   = (float*)alloc(1024*4);
    float* sg   = (float*)alloc(1024*4);
    float* cMat = (float*)alloc(1024*4);
    float* sMat = (float*)alloc(1024*4);
    int* cCnt = (int*)alloc(NN*4);
    int* cCur = (int*)alloc(NN*4);
    int* sCnt = (int*)alloc(NN*4);
    int* sCur = (int*)alloc(NN*4);
    int* cCnt0= (int*)alloc(NN*4);
    int* cCur0= (int*)alloc(NN*4);
    int* cRow = (int*)alloc((NN+1)*4);
    int* sRow = (int*)alloc((NN+1)*4);
    int* cRow0= (int*)alloc((NN+1)*4);
    int* cEl  = (int*)alloc(EE*4);
    int* sEl  = (int*)alloc(EE*4);
    int* cEl0 = (int*)alloc(EE*4);
    float* ccbuf = (float*)alloc((size_t)NN*32*4);
    unsigned short* tfbB = (unsigned short*)alloc((size_t)NN*64*2);
    unsigned short* wtC1 = (unsigned short*)alloc((size_t)2304*512*2);
    unsigned short* wtC2 = (unsigned short*)alloc((size_t)1280*256*2);
    unsigned short* wtC3 = (unsigned short*)alloc((size_t)384*128*2);
    unsigned short* wtS1 = (unsigned short*)alloc((size_t)2304*512*2);
    unsigned short* wtS2 = (unsigned short*)alloc((size_t)1280*256*2);
    unsigned short* wtS3 = (unsigned short*)alloc((size_t)384*128*2);
    unsigned short* wtCo = (unsigned short*)alloc((size_t)128*512*2);
    unsigned short* wtU  = (unsigned short*)alloc((size_t)512*64*2);
    unsigned short* cFcB = (unsigned short*)alloc((size_t)NN*512*2);
    unsigned short* sFcB = (unsigned short*)alloc((size_t)NN*512*2);
    float* h3c = (float*)alloc((size_t)NN*32*4);
    float* h3s = (float*)alloc((size_t)NN*32*4);
    unsigned short* tC = (unsigned short*)alloc((size_t)NN*2304*2);
    unsigned short* tS = (unsigned short*)alloc((size_t)NN*2304*2);
    float* tFc = (float*)tC;
    unsigned short* h1c = cFcB;
    unsigned short* h1s = sFcB;
    unsigned short* h2c = cFcB + (size_t)NN*256;
    unsigned short* h2s = sFcB + (size_t)NN*256;

    const int* cSrc = cEI; const int* cDst = cEI + EE;
    const int* sSrc = sEI; const int* sDst = sEI + EE;

    // ---- zero the contiguous accumulator block ----
    int zeroInts = (int)(((char*)cCur0 - (char*)d_ws)/4) + NN;
    zero_i<<<idiv(zeroInts,256),256,0,stream>>>((int*)d_ws, zeroInts);

    // ---- means + centering (bf16 out) ----
    colsum2<<<dim3(256,1,2),128,0,stream>>>(cF, cCol, sF, sCol);
    center2<<<dim3(NN*CC/1024,1,2),256,0,stream>>>(cF, cCol, (ushort4*)cFcB,
                                                   sF, sCol, (ushort4*)sFcB);

    // ---- weight transposes ----
    wtrans2z<<<dim3(2,16,18),128,0,stream>>>(cW1, sW1, wtC1, wtS1, 512, 256);
    wtrans2z<<<dim3(1,8,18),128,0,stream>>>(cW2, sW2, wtC2, wtS2, 256, 128);
    wtransz<<<dim3(idiv(384*128,256),1,2),256,0,stream>>>(cW3, wtC3, sW3, wtS3, 9,128,32, 384,128);
    wtransz<<<dim3(idiv(128*512,256),1,1),256,0,stream>>>(compW, wtCo, compW, wtCo, 1,512,32, 128,512);
    wtransz<<<dim3(idiv(512*64,256),1,1),256,0,stream>>>(unzW, wtU, unzW, wtU, 1,32,512, 512,64);

    // ---- CSR build (merged) ----
    csr_count3<<<dim3(idiv(EE,256),1,3),256,0,stream>>>(cDst, sDst, cSel, cCnt, sCnt, cCnt0);
    csr_scan3<<<dim3(1,1,3),1024,0,stream>>>(cCnt, sCnt, cCnt0, cRow, sRow, cRow0);
    csr_fill3<<<dim3(idiv(EE,256),1,3),256,0,stream>>>(cSrc,cDst,cSel, sSrc,sDst,sSel,
                                                       cRow,sRow,cRow0, cCur,sCur,cCur0,
                                                       cEl,sEl,cEl0);

    // ---- compress: tF = cFc@compW ; cc = bias + gather(sel==0) ----
    mfma_gemm<float><<<dim3(1,128,1),256,0,stream>>>(cFcB, wtCo, tFc,
                                                     cFcB, wtCo, tFc, 512, 128);
    gather4f<false><<<NN*8/256,256,0,stream>>>(cRow0,cEl0,tFc,compB,nullptr,ccbuf,128,5);

    // ---- L1 (both nets): gemm_db, conflict-free swizzle, 4 blk/CU ----
    gemm_db<16,unsigned short><<<dim3(18,128,2),256,0,stream>>>(cFcB, wtC1, tC,
                                                                sFcB, wtS1, tS, 2304);
    gather8z<unsigned short,true><<<dim3(2048,1,2),256,0,stream>>>(
        cRow,cEl,tC,cB1,h1c, sRow,sEl,tS,sB1,h1s, 2304, 8);
    // ---- L2 (both nets): gemm_db<8> ----
    gemm_db<8,unsigned short><<<dim3(10,128,2),256,0,stream>>>(h1c, wtC2, tC,
                                                               h1s, wtS2, tS, 1280);
    gather8z<unsigned short,true><<<dim3(1024,1,2),256,0,stream>>>(
        cRow,cEl,tC,cB2,h2c, sRow,sEl,tS,sB2,h2s, 1280, 7);
    // ---- L3 (both nets): round-5 mfma_gemm ----
    mfma_gemm<unsigned short><<<dim3(3,128,2),256,0,stream>>>(h2c, wtC3, tC,
                                                              h2s, wtS3, tS, 128, 384);
    gather8z<float,false><<<dim3(256,1,2),256,0,stream>>>(
        cRow,cEl,tC,cB3,h3c, sRow,sEl,tS,sB3,h3s, 384, 5);
    // ---- gram + fc (both nets) ----
    gram2<<<dim3(64,1,2),1024,0,stream>>>(h3c, cg, h3s, sg);
    fc2<<<dim3(1024,1,2),256,0,stream>>>(cg,cFW,cFB,cMat, sg,sFW,sFB,sMat);

    // ---- transmatrix + transfeature ----
    mm32_kernel<<<1,1024,0,stream>>>(sMat, cMat, Tmat);
    tf_cvt_kernel<<<NN*32/256,256,0,stream>>>(ccbuf, Tmat, tfbB);

    // ---- unzip: out = unzip_b + sMean + gather(sel==0) of tf @ unzip_W ----
    mfma_gemm<float><<<dim3(4,128,1),256,0,stream>>>(tfbB, wtU, tFc,
                                                     tfbB, wtU, tFc, 64, 512);
    gather4f<true><<<NN*128/256,256,0,stream>>>(cRow0,cEl0,tFc,unzB,sCol,out,512,9);
}